// Round 19
// baseline (404.814 us; speedup 1.0000x reference)
//
#include <hip/hip_runtime.h>
#include <cstdint>

#define B_    16
#define N_    128
#define P_    4096
#define M_    65536     // B_*P_
#define DIN   1024
#define DHID  512
#define DGEO  128
#define DEMB  200
#define NODEF 328       // DGEO + DEMB
#define NOBJ  151
#define OUTC  50
#define KGEO  656
#define KGEOP 672       // geo K padded to multiple of 32 (ring BK=32)

typedef __attribute__((ext_vector_type(8))) short bf16x8;
typedef __attribute__((ext_vector_type(4))) float f32x4;

typedef __attribute__((address_space(3))) unsigned char lds_u8;
typedef __attribute__((address_space(1))) unsigned char glb_u8;

static __device__ __forceinline__ void async_copy16(const void* g, void* l) {
  __builtin_amdgcn_global_load_lds((const glb_u8*)g, (lds_u8*)l, 16, 0, 0);
}

static __device__ __forceinline__ unsigned short f2b(float f) {
  union { float f; unsigned u; } v; v.f = f;
  unsigned r = v.u + 0x7fffu + ((v.u >> 16) & 1u);
  return (unsigned short)(r >> 16);
}
static __device__ __forceinline__ float b2f(unsigned short b) {
  union { unsigned u; float f; } v; v.u = ((unsigned)b) << 16;
  return v.f;
}
static __device__ __forceinline__ unsigned pack2(float a, float b) {
  return (unsigned)f2b(a) | ((unsigned)f2b(b) << 16);
}
static __device__ __forceinline__ void unpack8(uint4 raw, float* x) {
  x[0] = b2f(raw.x & 0xffffu); x[1] = b2f(raw.x >> 16);
  x[2] = b2f(raw.y & 0xffffu); x[3] = b2f(raw.y >> 16);
  x[4] = b2f(raw.z & 0xffffu); x[5] = b2f(raw.z >> 16);
  x[6] = b2f(raw.w & 0xffffu); x[7] = b2f(raw.w >> 16);
}

// ---- merged prologue: zero scat + all 4 weight transposes in one launch ----
#define ZN   131072
#define TV   (512 * 1024)
#define TG   (512 * KGEOP)
#define TF   (512 * 1024)
#define TC   (128 * 512)
#define PREP_TOT (ZN + TV + TG + TF + TC)
__global__ __launch_bounds__(256)
void prep_kernel(uint4* __restrict__ scat,
                 const float* __restrict__ vis_w, unsigned short* __restrict__ wT_vis,
                 const float* __restrict__ geo_w, unsigned short* __restrict__ wT_geo,
                 const float* __restrict__ fus_w, unsigned short* __restrict__ wT_fus,
                 const float* __restrict__ cls_w, unsigned short* __restrict__ wT_cls) {
  int idx = blockIdx.x * 256 + threadIdx.x;
  if (idx < ZN) { scat[idx] = make_uint4(0, 0, 0, 0); return; }
  idx -= ZN;
  if (idx < TV) {
    int n = idx >> 10, k = idx & 1023;
    wT_vis[idx] = f2b(vis_w[(size_t)k * 512 + n]);
    return;
  }
  idx -= TV;
  if (idx < TG) {
    int n = idx / KGEOP, k = idx - n * KGEOP;
    wT_geo[idx] = (k < KGEO) ? f2b(geo_w[(size_t)k * 512 + n]) : 0;
    return;
  }
  idx -= TG;
  if (idx < TF) {
    int n = idx >> 10, k = idx & 1023;
    wT_fus[idx] = f2b(fus_w[(size_t)k * 512 + n]);
    return;
  }
  idx -= TF;
  if (idx < TC) {
    int n = idx >> 9, k = idx & 511;
    wT_cls[idx] = (n < OUTC) ? f2b(cls_w[(size_t)k * OUTC + n]) : 0;
  }
}

// ---- per-node features (relu'd, bf16) ----
__global__ __launch_bounds__(128)
void node_kernel(const float* __restrict__ box, const float* __restrict__ plog,
                 const float* __restrict__ semw,
                 const float* __restrict__ w1, const float* __restrict__ b1,
                 const float* __restrict__ w2, const float* __restrict__ b2,
                 unsigned short* __restrict__ nodeFb) {
  const int node = blockIdx.x;
  const int t = threadIdx.x;
  __shared__ float sBox[9];
  __shared__ float sH[128];
  __shared__ float sE[NOBJ];
  __shared__ float sRed[4];
  if (t < 9) sBox[t] = box[node * 9 + t];
  float l0 = (t < NOBJ) ? plog[node * NOBJ + t] : -1e30f;
  float l1 = (t + 128 < NOBJ) ? plog[node * NOBJ + t + 128] : -1e30f;
  __syncthreads();
  float h = b1[t];
#pragma unroll
  for (int i = 0; i < 9; i++) h = fmaf(sBox[i], w1[i * 128 + t], h);
  h = fmaxf(h, 0.f);
  sH[t] = h;
  float mx = fmaxf(l0, l1);
#pragma unroll
  for (int off = 32; off >= 1; off >>= 1) mx = fmaxf(mx, __shfl_xor(mx, off));
  if ((t & 63) == 0) sRed[t >> 6] = mx;
  __syncthreads();
  mx = fmaxf(sRed[0], sRed[1]);
  float e0 = (t < NOBJ) ? expf(l0 - mx) : 0.f;
  float e1 = (t + 128 < NOBJ) ? expf(l1 - mx) : 0.f;
  if (t < NOBJ) sE[t] = e0;
  if (t + 128 < NOBJ) sE[t + 128] = e1;
  float sm = e0 + e1;
#pragma unroll
  for (int off = 32; off >= 1; off >>= 1) sm += __shfl_xor(sm, off);
  if ((t & 63) == 0) sRed[2 + (t >> 6)] = sm;
  __syncthreads();
  const float inv = 1.f / (sRed[2] + sRed[3]);
  float pv = b2[t];
  for (int i = 0; i < 128; i++) pv = fmaf(sH[i], w2[i * 128 + t], pv);
  nodeFb[(size_t)node * NODEF + t] = f2b(fmaxf(pv, 0.f));
  float a0 = 0.f, a1 = 0.f;
  const int d1 = (t + 128 < DEMB) ? (t + 128) : 0;
  for (int i = 0; i < NOBJ; i++) {
    float e = sE[i];
    a0 = fmaf(e, semw[i * DEMB + t], a0);
    a1 = fmaf(e, semw[i * DEMB + d1], a1);
  }
  nodeFb[(size_t)node * NODEF + 128 + t] = f2b(fmaxf(a0 * inv, 0.f));
  if (t + 128 < DEMB) nodeFb[(size_t)node * NODEF + 128 + t + 128] = f2b(fmaxf(a1 * inv, 0.f));
}

// ---- pair-XCD swizzle: bn-siblings land on the SAME XCD (nwg % 16 == 0) ----
static __device__ __forceinline__ int pair_swz(int bid, int nwg) {
  const int cpx2 = nwg >> 4;
  const int pr = bid >> 1, q = bid & 1;
  return (((pr & 7) * cpx2) + (pr >> 3)) * 2 + q;
}

// ---- 128x256 ring-2 GEMM, all-gload_lds staging (geo gather) + row-stats out ----
__global__ __launch_bounds__(512, 4)
void gemm_geo(const unsigned short* __restrict__ Bt, int Ktot,
              const float* __restrict__ bias,
              unsigned short* __restrict__ C, int ldcE, int ccol0,
              int NS, int NBN,
              const int* __restrict__ pidx,
              const unsigned short* __restrict__ nodeFb,
              const unsigned short* __restrict__ zsrc,
              float2* __restrict__ statsOut) {
  __shared__ __align__(16) unsigned char smem[49152];   // A 2x8K | B 2x16K @16K
  const int tid = threadIdx.x;
  const int lane = tid & 63, w = tid >> 6;
  const int swz = pair_swz(blockIdx.x, gridDim.x);
  const int bm = swz / NBN, bn = swz - bm * NBN;

  const int sslot = (tid & 3) ^ ((tid >> 3) & 3);
  const int srow = tid >> 2;
  const size_t ldbBy = (size_t)Ktot * 2;
  const unsigned char* bG = (const unsigned char*)Bt + (size_t)(bn * 256 + srow) * ldbBy + sslot * 16;

  int pr = bm * 128 + srow;
  int2 so = *(const int2*)(pidx + 2 * pr);
  int b = pr >> 12;
  const unsigned short* nbS = nodeFb + (size_t)((b << 7) + so.x) * NODEF;
  const unsigned short* nbO = nodeFb + (size_t)((b << 7) + so.y) * NODEF;

  auto stage = [&](int s) {
    const int slot = s & 1;
    unsigned char* la = smem + slot * 8192 + w * 1024;
    unsigned char* lb = smem + 16384 + slot * 16384 + w * 1024;
    const int e = s * 32 + sslot * 8;
    uintptr_t sel = (e < NODEF) ? (uintptr_t)(nbS + e)
                  : (e < KGEO)  ? (uintptr_t)(nbO + (e - NODEF))
                                : (uintptr_t)zsrc;
    async_copy16((const void*)sel, la);
    const unsigned char* sb = bG + (size_t)s * 64;
    async_copy16(sb, lb);
    async_copy16(sb + 128 * ldbBy, lb + 8192);
  };

  const int wm = w >> 2, wn = w & 3;
  const int frow = lane & 15;
  const int colb = (((lane >> 4) ^ ((frow >> 1) & 3)) << 4);
  const int aRowB = (wm * 64 + frow) * 64;
  const int bRowB = (wn * 64 + frow) * 64;

  f32x4 acc[4][4];
#pragma unroll
  for (int m = 0; m < 4; m++)
#pragma unroll
    for (int n = 0; n < 4; n++) acc[m][n] = (f32x4){0.f, 0.f, 0.f, 0.f};

  stage(0); stage(1);
#pragma unroll 1
  for (int s = 0; s < NS; ++s) {
    if (s == NS - 1) asm volatile("s_waitcnt vmcnt(0)" ::: "memory");
    else             asm volatile("s_waitcnt vmcnt(3)" ::: "memory");
    __builtin_amdgcn_s_barrier();
    __builtin_amdgcn_sched_barrier(0);
    const unsigned char* ab = smem + (s & 1) * 8192;
    const unsigned char* bb = smem + 16384 + (s & 1) * 16384;
    bf16x8 af[4];
#pragma unroll
    for (int m = 0; m < 4; m++) af[m] = *(const bf16x8*)(ab + aRowB + m * 1024 + colb);
    __builtin_amdgcn_s_setprio(1);
#pragma unroll
    for (int n = 0; n < 4; n++) {
      bf16x8 bf = *(const bf16x8*)(bb + bRowB + n * 1024 + colb);
#pragma unroll
      for (int m = 0; m < 4; m++)
        acc[m][n] = __builtin_amdgcn_mfma_f32_16x16x32_bf16(af[m], bf, acc[m][n], 0, 0, 0);
    }
    __builtin_amdgcn_s_setprio(0);
    __builtin_amdgcn_sched_barrier(0);
    __builtin_amdgcn_s_barrier();
    __builtin_amdgcn_sched_barrier(0);
    if (s + 2 < NS) stage(s + 2);
  }
  const int rb = bm * 128 + wm * 64 + ((lane >> 4) << 2);
  const int cb = bn * 256 + wn * 64 + frow;
  float bv[4];
#pragma unroll
  for (int n = 0; n < 4; n++) bv[n] = bias[cb + n * 16];
#pragma unroll
  for (int n = 0; n < 4; n++) {
    const int col = cb + n * 16;
#pragma unroll
    for (int m = 0; m < 4; m++)
#pragma unroll
      for (int i = 0; i < 4; i++)
        C[(size_t)(rb + m * 16 + i) * ldcE + ccol0 + col] = f2b(acc[m][n][i] + bv[n]);
  }
  const int slot = 8 + bn * 4 + wn;
#pragma unroll
  for (int m = 0; m < 4; m++)
#pragma unroll
    for (int i = 0; i < 4; i++) {
      float s = 0.f, s2 = 0.f;
#pragma unroll
      for (int n = 0; n < 4; n++) {
        float v = acc[m][n][i] + bv[n];
        s += v; s2 = fmaf(v, v, s2);
      }
#pragma unroll
      for (int off = 1; off <= 8; off <<= 1) { s += __shfl_xor(s, off); s2 += __shfl_xor(s2, off); }
      if (frow == 0) statsOut[(size_t)(rb + m * 16 + i) * 16 + slot] = make_float2(s, s2);
    }
}

// ---- 64x256 ring-2 GEMM, A f32+relu+cvt reg-staged (vis), 32-AGPR acc ----
// grid = (M/64)*NBN = 2048. 8 waves 2M x 4N, wave 32x64 -> acc[2][4] = 32 AGPR.
// LDS = A 2x4K + B 2x16K = 40 KB; ~82 regs -> target 6 waves/SIMD, 3 blocks/CU.
// A staging: 8 thr/row (asrow=tid>>3, ak=tid&7), each 1 uint4 f32 load (4 floats)
// -> ds_write_b64 to swizzled dest: slot16 (ak>>1)^((asrow>>1)&3), half (ak&1)*8.
// Per stage: 1 A uint4 (reg) + 2 B gload_lds = 3 vm events (fusLN-proven ledger):
//   issue order: head(s): issueA(s+2); end(s): issueB(s+2). Newer-than-B(s) at
//   head of s = {A(s+1), B(s+1)x2} = 3 -> vmcnt(3); s==NS-1 -> vmcnt(0).
__global__ __launch_bounds__(512, 6)
void gemm_vis64(const float* __restrict__ A,            // f32, lda = 1024
                const unsigned short* __restrict__ Bt,  // [512][1024] bf16
                const float* __restrict__ bias,
                unsigned short* __restrict__ C, int ldcE, int ccol0,
                int NBN, float2* __restrict__ statsOut) {
  constexpr int NS = 32;                               // K=1024 / BK=32
  __shared__ __align__(16) unsigned char smem[40960];  // A 2x4K | B 2x16K @8192
  const int tid = threadIdx.x;
  const int lane = tid & 63, w = tid >> 6;
  const int swz = pair_swz(blockIdx.x, gridDim.x);
  const int bm = swz / NBN, bn = swz - bm * NBN;       // bm 0..1023, bn 0..1

  // A staging geometry: row asrow (0..63), float chunk ak (0..7) of the 32-float k-tile
  const int asrow = tid >> 3, ak = tid & 7;
  const float* aG = A + (size_t)(bm * 64 + asrow) * 1024 + ak * 4;
  unsigned char* aDst = smem + asrow * 64 + (((ak >> 1) ^ ((asrow >> 1) & 3)) << 4) + (ak & 1) * 8;
  // B staging geometry (unchanged pattern): row bsrow (0..127), slot16 bslot
  const int bslot = (tid & 3) ^ ((tid >> 3) & 3);
  const int bsrow = tid >> 2;
  const unsigned char* bG = (const unsigned char*)Bt + (size_t)(bn * 256 + bsrow) * 2048 + bslot * 16;
  unsigned char* lbBase = smem + 8192 + w * 1024;

  uint4 ra0, ra1;
  auto issueA = [&](int s, uint4* ra) {
    *ra = *(const uint4*)(aG + (size_t)s * 32);
  };
  auto issueB = [&](int s) {
    const int slot = s & 1;
    const unsigned char* sb = bG + (size_t)s * 64;
    async_copy16(sb, lbBase + slot * 16384);
    async_copy16(sb + 128 * 2048, lbBase + slot * 16384 + 8192);
  };
  auto writeA = [&](int s, const uint4* ra) {
    float x0 = fmaxf(__uint_as_float(ra->x), 0.f);
    float x1 = fmaxf(__uint_as_float(ra->y), 0.f);
    float x2 = fmaxf(__uint_as_float(ra->z), 0.f);
    float x3 = fmaxf(__uint_as_float(ra->w), 0.f);
    uint2 u;
    u.x = pack2(x0, x1); u.y = pack2(x2, x3);
    *(uint2*)(aDst + (s & 1) * 4096) = u;
  };

  const int wm = w >> 2, wn = w & 3;                   // 2M x 4N waves, 32x64 each
  const int frow = lane & 15;
  const int colb = (((lane >> 4) ^ ((frow >> 1) & 3)) << 4);
  const int aRowB = (wm * 32 + frow) * 64;
  const int bRowB = (wn * 64 + frow) * 64;

  f32x4 acc[2][4];
#pragma unroll
  for (int m = 0; m < 2; m++)
#pragma unroll
    for (int n = 0; n < 4; n++) acc[m][n] = (f32x4){0.f, 0.f, 0.f, 0.f};

  issueA(0, &ra0); issueB(0);
  issueA(1, &ra1); issueB(1);

#pragma unroll 1
  for (int s = 0; s < NS; s += 2) {
#pragma unroll
    for (int half = 0; half < 2; half++) {
      const int sc = s + half;
      uint4* raC = half ? &ra1 : &ra0;
      if (sc == NS - 1) asm volatile("s_waitcnt vmcnt(0)" ::: "memory");
      else              asm volatile("s_waitcnt vmcnt(3)" ::: "memory");
      __builtin_amdgcn_sched_barrier(0);
      writeA(sc, raC);                       // slot sc&1: readers done at sc-2
      if (sc + 2 < NS) issueA(sc + 2, raC);  // reg load — safe before barrier
      asm volatile("s_waitcnt lgkmcnt(0)" ::: "memory");
      __builtin_amdgcn_s_barrier();
      __builtin_amdgcn_sched_barrier(0);
      const unsigned char* ab = smem + (sc & 1) * 4096;
      const unsigned char* bb = smem + 8192 + (sc & 1) * 16384;
      bf16x8 af[2];
#pragma unroll
      for (int m = 0; m < 2; m++) af[m] = *(const bf16x8*)(ab + aRowB + m * 1024 + colb);
      __builtin_amdgcn_s_setprio(1);
#pragma unroll
      for (int n = 0; n < 4; n++) {
        bf16x8 bf = *(const bf16x8*)(bb + bRowB + n * 1024 + colb);
#pragma unroll
        for (int m = 0; m < 2; m++)
          acc[m][n] = __builtin_amdgcn_mfma_f32_16x16x32_bf16(af[m], bf, acc[m][n], 0, 0, 0);
      }
      __builtin_amdgcn_s_setprio(0);
      __builtin_amdgcn_sched_barrier(0);
      __builtin_amdgcn_s_barrier();          // readers of slots sc&1 done
      __builtin_amdgcn_sched_barrier(0);
      if (sc + 2 < NS) issueB(sc + 2);       // overwrites B slot sc&1 safely
    }
  }
  const int rb = bm * 64 + wm * 32 + ((lane >> 4) << 2);
  const int cb = bn * 256 + wn * 64 + frow;
  float bv[4];
#pragma unroll
  for (int n = 0; n < 4; n++) bv[n] = bias[cb + n * 16];
#pragma unroll
  for (int n = 0; n < 4; n++) {
    const int col = cb + n * 16;
#pragma unroll
    for (int m = 0; m < 2; m++)
#pragma unroll
      for (int i = 0; i < 4; i++)
        C[(size_t)(rb + m * 16 + i) * ldcE + ccol0 + col] = f2b(acc[m][n][i] + bv[n]);
  }
  const int slot = bn * 4 + wn;
#pragma unroll
  for (int m = 0; m < 2; m++)
#pragma unroll
    for (int i = 0; i < 4; i++) {
      float s = 0.f, s2 = 0.f;
#pragma unroll
      for (int n = 0; n < 4; n++) {
        float v = acc[m][n][i] + bv[n];
        s += v; s2 = fmaf(v, v, s2);
      }
#pragma unroll
      for (int off = 1; off <= 8; off <<= 1) { s += __shfl_xor(s, off); s2 += __shfl_xor(s2, off); }
      if (frow == 0) statsOut[(size_t)(rb + m * 16 + i) * 16 + slot] = make_float2(s, s2);
    }
}

// ---- 128x256 ring-2 GEMM, FUSED LayerNorm+ReLU A-staging (fus) + stats2 out ----
__global__ __launch_bounds__(512, 4)
void gemm_fusLN(const unsigned short* __restrict__ A,   // fused bf16 [M][1024]
                const unsigned short* __restrict__ Bt,  // wT_fus [512][1024]
                const float2* __restrict__ statsIn,     // [M][16] partial (s,s2)
                const float* __restrict__ lng, const float* __restrict__ lnb,
                const float* __restrict__ bias,
                unsigned short* __restrict__ C,         // fused2 [M][512]
                int NBN, float2* __restrict__ statsOut) {
  constexpr int NS = 32;
  __shared__ __align__(16) unsigned char smem[57344];
  const int tid = threadIdx.x;
  const int lane = tid & 63, w = tid >> 6;
  const int swz = pair_swz(blockIdx.x, gridDim.x);
  const int bm = swz / NBN, bn = swz - bm * NBN;

  const int sslot = (tid & 3) ^ ((tid >> 3) & 3);
  const int srow = tid >> 2;
  const unsigned short* aG = A + (size_t)(bm * 128 + srow) * 1024 + sslot * 8;
  const unsigned char* bG = (const unsigned char*)Bt + (size_t)(bn * 256 + srow) * 2048 + sslot * 16;
  unsigned char* laBase = smem + srow * 64 + (tid & 3) * 16;
  unsigned char* lbBase = smem + 16384 + w * 1024;

  {
    const float* src = (w < 4) ? (lng + w * 256 + lane * 4)
                               : (lnb + (w - 4) * 256 + lane * 4);
    unsigned char* dst = smem + 49152 + w * 1024;
    async_copy16(src, dst);
  }
  asm volatile("s_waitcnt vmcnt(0)" ::: "memory");
  __builtin_amdgcn_s_barrier();

  float ssum = 0.f, ssq = 0.f;
  {
    const float2* sp = statsIn + (size_t)(bm * 128 + srow) * 16;
#pragma unroll
    for (int j = 0; j < 16; j++) { float2 p = sp[j]; ssum += p.x; ssq += p.y; }
  }
  const float mu = ssum * (1.f / 1024.f);
  const float rs = rsqrtf(ssq * (1.f / 1024.f) - mu * mu + 1e-5f);
  const float* gl = (const float*)(smem + 49152);
  const float* bl = (const float*)(smem + 53248);

  uint4 ra0, ra1;

  auto issueA = [&](int s, uint4* ra) {
    *ra = *(const uint4*)(aG + (size_t)s * 32);
  };
  auto issueB = [&](int s) {
    const int slot = s & 1;
    const unsigned char* sb = bG + (size_t)s * 64;
    async_copy16(sb, lbBase + slot * 16384);
    async_copy16(sb + 128 * 2048, lbBase + slot * 16384 + 8192);
  };
  auto writeA = [&](int s, const uint4* ra) {
    const int slot = s & 1;
    const int k0 = s * 32 + sslot * 8;
    float x[8]; unpack8(*ra, x);
    float4 g0 = *(const float4*)(gl + k0), g1 = *(const float4*)(gl + k0 + 4);
    float4 t0 = *(const float4*)(bl + k0), t1 = *(const float4*)(bl + k0 + 4);
    float y0 = fmaxf(fmaf((x[0] - mu) * rs, g0.x, t0.x), 0.f);
    float y1 = fmaxf(fmaf((x[1] - mu) * rs, g0.y, t0.y), 0.f);
    float y2 = fmaxf(fmaf((x[2] - mu) * rs, g0.z, t0.z), 0.f);
    float y3 = fmaxf(fmaf((x[3] - mu) * rs, g0.w, t0.w), 0.f);
    float y4 = fmaxf(fmaf((x[4] - mu) * rs, g1.x, t1.x), 0.f);
    float y5 = fmaxf(fmaf((x[5] - mu) * rs, g1.y, t1.y), 0.f);
    float y6 = fmaxf(fmaf((x[6] - mu) * rs, g1.z, t1.z), 0.f);
    float y7 = fmaxf(fmaf((x[7] - mu) * rs, g1.w, t1.w), 0.f);
    uint4 u;
    u.x = pack2(y0, y1); u.y = pack2(y2, y3);
    u.z = pack2(y4, y5); u.w = pack2(y6, y7);
    *(uint4*)(laBase + slot * 8192) = u;
  };

  const int wm = w >> 2, wn = w & 3;
  const int frow = lane & 15;
  const int colb = (((lane >> 4) ^ ((frow >> 1) & 3)) << 4);
  const int aRowB = (wm * 64 + frow) * 64;
  const int bRowB = (wn * 64 + frow) * 64;

  f32x4 acc[4][4];
#pragma unroll
  for (int m = 0; m < 4; m++)
#pragma unroll
    for (int n = 0; n < 4; n++) acc[m][n] = (f32x4){0.f, 0.f, 0.f, 0.f};

  issueA(0, &ra0); issueB(0);
  issueA(1, &ra1); issueB(1);

#pragma unroll 1
  for (int s = 0; s < NS; s += 2) {
#pragma unroll
    for (int half = 0; half < 2; half++) {
      const int sc = s + half;
      uint4* raC = half ? &ra1 : &ra0;
      if (sc == NS - 1) asm volatile("s_waitcnt vmcnt(0)" ::: "memory");
      else              asm volatile("s_waitcnt vmcnt(3)" ::: "memory");
      __builtin_amdgcn_sched_barrier(0);
      writeA(sc, raC);
      if (sc + 2 < NS) issueA(sc + 2, raC);
      asm volatile("s_waitcnt lgkmcnt(0)" ::: "memory");
      __builtin_amdgcn_s_barrier();
      __builtin_amdgcn_sched_barrier(0);
      const unsigned char* ab = smem + (sc & 1) * 8192;
      const unsigned char* bb = smem + 16384 + (sc & 1) * 16384;
      bf16x8 af[4];
#pragma unroll
      for (int m = 0; m < 4; m++) af[m] = *(const bf16x8*)(ab + aRowB + m * 1024 + colb);
      __builtin_amdgcn_s_setprio(1);
#pragma unroll
      for (int n = 0; n < 4; n++) {
        bf16x8 bf = *(const bf16x8*)(bb + bRowB + n * 1024 + colb);
#pragma unroll
        for (int m = 0; m < 4; m++)
          acc[m][n] = __builtin_amdgcn_mfma_f32_16x16x32_bf16(af[m], bf, acc[m][n], 0, 0, 0);
      }
      __builtin_amdgcn_s_setprio(0);
      __builtin_amdgcn_sched_barrier(0);
      __builtin_amdgcn_s_barrier();
      __builtin_amdgcn_sched_barrier(0);
      if (sc + 2 < NS) issueB(sc + 2);
    }
  }
  const int rb = bm * 128 + wm * 64 + ((lane >> 4) << 2);
  const int cb = bn * 256 + wn * 64 + frow;
  float bv[4];
#pragma unroll
  for (int n = 0; n < 4; n++) bv[n] = bias[cb + n * 16];
#pragma unroll
  for (int n = 0; n < 4; n++) {
    const int col = cb + n * 16;
#pragma unroll
    for (int m = 0; m < 4; m++)
#pragma unroll
      for (int i = 0; i < 4; i++)
        C[(size_t)(rb + m * 16 + i) * 512 + col] = f2b(acc[m][n][i] + bv[n]);
  }
  const int slot = bn * 4 + wn;
#pragma unroll
  for (int m = 0; m < 4; m++)
#pragma unroll
    for (int i = 0; i < 4; i++) {
      float s = 0.f, s2 = 0.f;
#pragma unroll
      for (int n = 0; n < 4; n++) {
        float v = acc[m][n][i] + bv[n];
        s += v; s2 = fmaf(v, v, s2);
      }
#pragma unroll
      for (int off = 1; off <= 8; off <<= 1) { s += __shfl_xor(s, off); s2 += __shfl_xor(s2, off); }
      if (frow == 0) statsOut[(size_t)(rb + m * 16 + i) * 8 + slot] = make_float2(s, s2);
    }
}

// ---- 128x128 ring-2 cls GEMM with FUSED LN+ReLU A-staging + score scatter ----
__global__ __launch_bounds__(512, 4)
void gemm_clsLN(const unsigned short* __restrict__ A,   // fused2 bf16 [M][512]
                const unsigned short* __restrict__ Bt,  // wT_cls [128][512]
                const float2* __restrict__ statsIn,     // [M][8] partial (s,s2)
                const float* __restrict__ lng, const float* __restrict__ lnb,
                const float* __restrict__ bias,
                float* __restrict__ C,                  // logits [M][50]
                const int* __restrict__ pidx,
                unsigned long long* __restrict__ scat) {
  constexpr int NS = 16;
  __shared__ __align__(16) unsigned char smem[36864];
  const int tid = threadIdx.x;
  const int lane = tid & 63, w = tid >> 6;
  const int cpx = gridDim.x >> 3;
  const int bm = (blockIdx.x & 7) * cpx + (blockIdx.x >> 3);

  const int sslot = (tid & 3) ^ ((tid >> 3) & 3);
  const int srow = tid >> 2;
  const unsigned short* aG = A + (size_t)(bm * 128 + srow) * 512 + sslot * 8;
  const unsigned char* bG = (const unsigned char*)Bt + (size_t)srow * 1024 + sslot * 16;
  unsigned char* laBase = smem + srow * 64 + (tid & 3) * 16;
  unsigned char* lbBase = smem + 16384 + w * 1024;

  if (w < 4) {
    const float* src = (w < 2) ? (lng + w * 256 + lane * 4)
                               : (lnb + (w - 2) * 256 + lane * 4);
    unsigned char* dst = smem + 32768 + ((w < 2) ? w * 1024 : 2048 + (w - 2) * 1024);
    async_copy16(src, dst);
  }
  asm volatile("s_waitcnt vmcnt(0)" ::: "memory");
  __builtin_amdgcn_s_barrier();

  float ssum = 0.f, ssq = 0.f;
  {
    const float2* sp = statsIn + (size_t)(bm * 128 + srow) * 8;
#pragma unroll
    for (int j = 0; j < 8; j++) { float2 p = sp[j]; ssum += p.x; ssq += p.y; }
  }
  const float mu = ssum * (1.f / 512.f);
  const float rs = rsqrtf(ssq * (1.f / 512.f) - mu * mu + 1e-5f);
  const float* gl = (const float*)(smem + 32768);
  const float* bl = (const float*)(smem + 34816);

  uint4 ra0, ra1;
  auto issueA = [&](int s, uint4* ra) { *ra = *(const uint4*)(aG + (size_t)s * 32); };
  auto issueB = [&](int s) {
    async_copy16(bG + (size_t)s * 64, lbBase + (s & 1) * 8192);
  };
  auto writeA = [&](int s, const uint4* ra) {
    const int slot = s & 1;
    const int k0 = s * 32 + sslot * 8;
    float x[8]; unpack8(*ra, x);
    float4 g0 = *(const float4*)(gl + k0), g1 = *(const float4*)(gl + k0 + 4);
    float4 t0 = *(const float4*)(bl + k0), t1 = *(const float4*)(bl + k0 + 4);
    float y0 = fmaxf(fmaf((x[0] - mu) * rs, g0.x, t0.x), 0.f);
    float y1 = fmaxf(fmaf((x[1] - mu) * rs, g0.y, t0.y), 0.f);
    float y2 = fmaxf(fmaf((x[2] - mu) * rs, g0.z, t0.z), 0.f);
    float y3 = fmaxf(fmaf((x[3] - mu) * rs, g0.w, t0.w), 0.f);
    float y4 = fmaxf(fmaf((x[4] - mu) * rs, g1.x, t1.x), 0.f);
    float y5 = fmaxf(fmaf((x[5] - mu) * rs, g1.y, t1.y), 0.f);
    float y6 = fmaxf(fmaf((x[6] - mu) * rs, g1.z, t1.z), 0.f);
    float y7 = fmaxf(fmaf((x[7] - mu) * rs, g1.w, t1.w), 0.f);
    uint4 u;
    u.x = pack2(y0, y1); u.y = pack2(y2, y3);
    u.z = pack2(y4, y5); u.w = pack2(y6, y7);
    *(uint4*)(laBase + slot * 8192) = u;
  };

  const int wm = w >> 1, wn = w & 1;
  const int frow = lane & 15;
  const int colb = (((lane >> 4) ^ ((frow >> 1) & 3)) << 4);
  const int aRowB = (wm * 32 + frow) * 64;
  const int bRowB = (wn * 64 + frow) * 64;

  f32x4 acc[2][4];
#pragma unroll
  for (int m = 0; m < 2; m++)
#pragma unroll
    for (int n = 0; n < 4; n++) acc[m][n] = (f32x4){0.f, 0.f, 0.f, 0.f};

  issueA(0, &ra0); issueB(0);
  issueA(1, &ra1); issueB(1);

#pragma unroll 1
  for (int s = 0; s < NS; s += 2) {
#pragma unroll
    for (int half = 0; half < 2; half++) {
      const int sc = s + half;
      uint4* raC = half ? &ra1 : &ra0;
      if (sc == NS - 1) asm volatile("s_waitcnt vmcnt(0)" ::: "memory");
      else              asm volatile("s_waitcnt vmcnt(2)" ::: "memory");
      __builtin_amdgcn_sched_barrier(0);
      writeA(sc, raC);
      if (sc + 2 < NS) issueA(sc + 2, raC);
      asm volatile("s_waitcnt lgkmcnt(0)" ::: "memory");
      __builtin_amdgcn_s_barrier();
      __builtin_amdgcn_sched_barrier(0);
      const unsigned char* ab = smem + (sc & 1) * 8192;
      const unsigned char* bb = smem + 16384 + (sc & 1) * 8192;
      bf16x8 af[2];
#pragma unroll
      for (int m = 0; m < 2; m++) af[m] = *(const bf16x8*)(ab + aRowB + m * 1024 + colb);
      __builtin_amdgcn_s_setprio(1);
#pragma unroll
      for (int n = 0; n < 4; n++) {
        bf16x8 bf = *(const bf16x8*)(bb + bRowB + n * 1024 + colb);
#pragma unroll
        for (int m = 0; m < 2; m++)
          acc[m][n] = __builtin_amdgcn_mfma_f32_16x16x32_bf16(af[m], bf, acc[m][n], 0, 0, 0);
      }
      __builtin_amdgcn_s_setprio(0);
      __builtin_amdgcn_sched_barrier(0);
      __builtin_amdgcn_s_barrier();
      __builtin_amdgcn_sched_barrier(0);
      if (sc + 2 < NS) issueB(sc + 2);
    }
  }
  const int rb = bm * 128 + wm * 32 + ((lane >> 4) << 2);
  const int cbl = wn * 64 + frow;
#pragma unroll
  for (int n = 0; n < 4; n++) {
    const int col = cbl + n * 16;
    const float bv = (col < OUTC) ? bias[col] : 0.f;
#pragma unroll
    for (int m = 0; m < 2; m++)
#pragma unroll
      for (int i = 0; i < 4; i++) {
        const int row = rb + m * 16 + i;
        if (col < OUTC) C[(size_t)row * OUTC + col] = acc[m][n][i] + bv;
      }
  }
  if (wn == 0) {
#pragma unroll
    for (int m = 0; m < 2; m++)
#pragma unroll
      for (int i = 0; i < 4; i++) {
        float mx = -1e30f;
#pragma unroll
        for (int n = 0; n < 4; n++) {
          const int col = n * 16 + frow;
          float v = acc[m][n][i] + ((col < OUTC) ? bias[col] : 0.f);
          if (col < OUTC) mx = fmaxf(mx, v);
        }
        mx = fmaxf(mx, __shfl_xor(mx, 1));
        mx = fmaxf(mx, __shfl_xor(mx, 2));
        mx = fmaxf(mx, __shfl_xor(mx, 4));
        mx = fmaxf(mx, __shfl_xor(mx, 8));
        if (frow == 0) {
          const int row = rb + m * 16 + i;
          float sc = 1.f / (1.f + expf(-mx));
          int b = row >> 12, p = row & 4095;
          int s = pidx[2 * row], o = pidx[2 * row + 1];
          unsigned long long key = (((unsigned long long)(p + 1)) << 32) |
                                   (unsigned long long)__float_as_uint(sc);
          atomicMax(&scat[((size_t)(b * N_ + s) << 7) + o], key);
        }
      }
  }
}

__global__ void relmat_kernel(const unsigned long long* __restrict__ scat, float* __restrict__ out) {
  int i = blockIdx.x * blockDim.x + threadIdx.x;
  if (i >= B_ * N_ * N_) return;
  unsigned long long v = scat[i];
  out[i] = v ? __uint_as_float((unsigned)(v & 0xffffffffu)) : 0.f;
}

extern "C" void kernel_launch(void* const* d_in, const int* in_sizes, int n_in,
                              void* d_out, int out_size, void* d_ws, size_t ws_size,
                              hipStream_t stream) {
  const float* visual_feat = (const float*)d_in[0];
  const float* box_info    = (const float*)d_in[1];
  const float* pred_logits = (const float*)d_in[2];
  const int*   pair_idx    = (const int*)d_in[3];
  const float* obj_sem_w   = (const float*)d_in[4];
  const float* pos_w1 = (const float*)d_in[5];
  const float* pos_b1 = (const float*)d_in[6];
  const float* pos_w2 = (const float*)d_in[7];
  const float* pos_b2 = (const float*)d_in[8];
  const float* vis_w  = (const float*)d_in[9];
  const float* vis_b  = (const float*)d_in[10];
  const float* geo_w  = (const float*)d_in[11];
  const float* geo_b  = (const float*)d_in[12];
  const float* fus_g  = (const float*)d_in[13];
  const float* fus_bt = (const float*)d_in[14];
  const float* fus_w  = (const float*)d_in[15];
  const float* fus_b  = (const float*)d_in[16];
  const float* cls_g  = (const float*)d_in[17];
  const float* cls_bt = (const float*)d_in[18];
  const float* cls_w  = (const float*)d_in[19];
  const float* cls_b  = (const float*)d_in[20];

  char* ws = (char*)d_ws;
  size_t off = 0;
  auto alloc = [&](size_t bytes) { char* p = ws + off; off += (bytes + 255) & ~(size_t)255; return p; };
  unsigned short* fused = (unsigned short*)alloc((size_t)M_ * 1024 * 2);      // 134 MB
  unsigned short* fused2 = (unsigned short*)alloc((size_t)M_ * 512 * 2);      // 67 MB
  unsigned short* nodeFb = (unsigned short*)alloc((size_t)B_ * N_ * NODEF * 2);
  unsigned short* wT_vis = (unsigned short*)alloc((size_t)512 * 1024 * 2);
  unsigned short* wT_geo = (unsigned short*)alloc((size_t)512 * KGEOP * 2);
  unsigned short* wT_fus = (unsigned short*)alloc((size_t)512 * 1024 * 2);
  unsigned short* wT_cls = (unsigned short*)alloc((size_t)128 * 512 * 2);
  unsigned long long* scat = (unsigned long long*)alloc((size_t)B_ * N_ * N_ * 8);
  float2* statsP1 = (float2*)alloc((size_t)M_ * 16 * 8);                      // 8 MB
  float2* statsP2 = (float2*)alloc((size_t)M_ * 8 * 8);                       // 4 MB

  float* out_logits = (float*)d_out;
  float* out_rel = out_logits + (size_t)M_ * OUTC;

  prep_kernel<<<dim3((PREP_TOT + 255) / 256), 256, 0, stream>>>(
      (uint4*)scat, vis_w, wT_vis, geo_w, wT_geo, fus_w, wT_fus, cls_w, wT_cls);
  node_kernel<<<dim3(B_ * N_), 128, 0, stream>>>(box_info, pred_logits, obj_sem_w,
                                                 pos_w1, pos_b1, pos_w2, pos_b2, nodeFb);
  // geo: gather GEMM -> fused[:,512:] + partial row stats (slots 8..15)
  gemm_geo<<<dim3(1024), 512, 0, stream>>>(wT_geo, KGEOP, geo_b,
                                           fused, 1024, 512, KGEOP / 32, 2,
                                           pair_idx, nodeFb, (const unsigned short*)scat,
                                           statsP1);
  // vis: 64x256 f32+relu GEMM -> fused[:,0:512] + partial row stats (slots 0..7)
  gemm_vis64<<<dim3(2048), 512, 0, stream>>>(visual_feat, wT_vis, vis_b,
                                             fused, 1024, 0, 2, statsP1);
  // fus: LN(stats combine)+relu in A-staging -> fused2 + partial stats2 (8 slots)
  gemm_fusLN<<<dim3(1024), 512, 0, stream>>>(fused, wT_fus, statsP1, fus_g, fus_bt,
                                             fus_b, fused2, 2, statsP2);
  // cls: LN(stats2)+relu in A-staging -> logits + fused score scatter
  gemm_clsLN<<<dim3(512), 512, 0, stream>>>(fused2, wT_cls, statsP2, cls_g, cls_bt,
                                            cls_b, out_logits, pair_idx, scat);
  relmat_kernel<<<dim3((B_ * N_ * N_) / 256), 256, 0, stream>>>(scat, out_rel);
}

// Round 20
// 373.701 us; speedup vs baseline: 1.0833x; 1.0833x over previous
//
#include <hip/hip_runtime.h>
#include <cstdint>

#define B_    16
#define N_    128
#define P_    4096
#define M_    65536     // B_*P_
#define DIN   1024
#define DHID  512
#define DGEO  128
#define DEMB  200
#define NODEF 328       // DGEO + DEMB
#define NOBJ  151
#define OUTC  50
#define KGEO  656
#define KGEOP 672       // geo K padded to multiple of 32 (ring BK=32)

typedef __attribute__((ext_vector_type(8))) short bf16x8;
typedef __attribute__((ext_vector_type(4))) float f32x4;

typedef __attribute__((address_space(3))) unsigned char lds_u8;
typedef __attribute__((address_space(1))) unsigned char glb_u8;

static __device__ __forceinline__ void async_copy16(const void* g, void* l) {
  __builtin_amdgcn_global_load_lds((const glb_u8*)g, (lds_u8*)l, 16, 0, 0);
}

static __device__ __forceinline__ unsigned short f2b(float f) {
  union { float f; unsigned u; } v; v.f = f;
  unsigned r = v.u + 0x7fffu + ((v.u >> 16) & 1u);
  return (unsigned short)(r >> 16);
}
static __device__ __forceinline__ float b2f(unsigned short b) {
  union { unsigned u; float f; } v; v.u = ((unsigned)b) << 16;
  return v.f;
}
static __device__ __forceinline__ unsigned pack2(float a, float b) {
  return (unsigned)f2b(a) | ((unsigned)f2b(b) << 16);
}
static __device__ __forceinline__ void unpack8(uint4 raw, float* x) {
  x[0] = b2f(raw.x & 0xffffu); x[1] = b2f(raw.x >> 16);
  x[2] = b2f(raw.y & 0xffffu); x[3] = b2f(raw.y >> 16);
  x[4] = b2f(raw.z & 0xffffu); x[5] = b2f(raw.z >> 16);
  x[6] = b2f(raw.w & 0xffffu); x[7] = b2f(raw.w >> 16);
}

// ---- merged prologue: zero scat + all 4 weight transposes in one launch ----
#define ZN   131072                    // scat zero, uint4 count (2 MB)
#define TV   (512 * 1024)              // wT_vis elems
#define TG   (512 * KGEOP)             // wT_geo elems
#define TF   (512 * 1024)              // wT_fus elems
#define TC   (128 * 512)               // wT_cls elems
#define PREP_TOT (ZN + TV + TG + TF + TC)
__global__ __launch_bounds__(256)
void prep_kernel(uint4* __restrict__ scat,
                 const float* __restrict__ vis_w, unsigned short* __restrict__ wT_vis,
                 const float* __restrict__ geo_w, unsigned short* __restrict__ wT_geo,
                 const float* __restrict__ fus_w, unsigned short* __restrict__ wT_fus,
                 const float* __restrict__ cls_w, unsigned short* __restrict__ wT_cls) {
  int idx = blockIdx.x * 256 + threadIdx.x;
  if (idx < ZN) { scat[idx] = make_uint4(0, 0, 0, 0); return; }
  idx -= ZN;
  if (idx < TV) {
    int n = idx >> 10, k = idx & 1023;
    wT_vis[idx] = f2b(vis_w[(size_t)k * 512 + n]);
    return;
  }
  idx -= TV;
  if (idx < TG) {
    int n = idx / KGEOP, k = idx - n * KGEOP;
    wT_geo[idx] = (k < KGEO) ? f2b(geo_w[(size_t)k * 512 + n]) : 0;
    return;
  }
  idx -= TG;
  if (idx < TF) {
    int n = idx >> 10, k = idx & 1023;
    wT_fus[idx] = f2b(fus_w[(size_t)k * 512 + n]);
    return;
  }
  idx -= TF;
  if (idx < TC) {
    int n = idx >> 9, k = idx & 511;
    wT_cls[idx] = (n < OUTC) ? f2b(cls_w[(size_t)k * OUTC + n]) : 0;
  }
}

// ---- per-node features (relu'd, bf16): nodeFb[node] = [relu(pos)(128), relu(sem)(200)] ----
__global__ __launch_bounds__(128)
void node_kernel(const float* __restrict__ box, const float* __restrict__ plog,
                 const float* __restrict__ semw,
                 const float* __restrict__ w1, const float* __restrict__ b1,
                 const float* __restrict__ w2, const float* __restrict__ b2,
                 unsigned short* __restrict__ nodeFb) {
  const int node = blockIdx.x;
  const int t = threadIdx.x;
  __shared__ float sBox[9];
  __shared__ float sH[128];
  __shared__ float sE[NOBJ];
  __shared__ float sRed[4];
  if (t < 9) sBox[t] = box[node * 9 + t];
  float l0 = (t < NOBJ) ? plog[node * NOBJ + t] : -1e30f;
  float l1 = (t + 128 < NOBJ) ? plog[node * NOBJ + t + 128] : -1e30f;
  __syncthreads();
  float h = b1[t];
#pragma unroll
  for (int i = 0; i < 9; i++) h = fmaf(sBox[i], w1[i * 128 + t], h);
  h = fmaxf(h, 0.f);
  sH[t] = h;
  float mx = fmaxf(l0, l1);
#pragma unroll
  for (int off = 32; off >= 1; off >>= 1) mx = fmaxf(mx, __shfl_xor(mx, off));
  if ((t & 63) == 0) sRed[t >> 6] = mx;
  __syncthreads();
  mx = fmaxf(sRed[0], sRed[1]);
  float e0 = (t < NOBJ) ? expf(l0 - mx) : 0.f;
  float e1 = (t + 128 < NOBJ) ? expf(l1 - mx) : 0.f;
  if (t < NOBJ) sE[t] = e0;
  if (t + 128 < NOBJ) sE[t + 128] = e1;
  float sm = e0 + e1;
#pragma unroll
  for (int off = 32; off >= 1; off >>= 1) sm += __shfl_xor(sm, off);
  if ((t & 63) == 0) sRed[2 + (t >> 6)] = sm;
  __syncthreads();
  const float inv = 1.f / (sRed[2] + sRed[3]);
  float pv = b2[t];
  for (int i = 0; i < 128; i++) pv = fmaf(sH[i], w2[i * 128 + t], pv);
  nodeFb[(size_t)node * NODEF + t] = f2b(fmaxf(pv, 0.f));
  float a0 = 0.f, a1 = 0.f;
  const int d1 = (t + 128 < DEMB) ? (t + 128) : 0;
  for (int i = 0; i < NOBJ; i++) {
    float e = sE[i];
    a0 = fmaf(e, semw[i * DEMB + t], a0);
    a1 = fmaf(e, semw[i * DEMB + d1], a1);
  }
  nodeFb[(size_t)node * NODEF + 128 + t] = f2b(fmaxf(a0 * inv, 0.f));
  if (t + 128 < DEMB) nodeFb[(size_t)node * NODEF + 128 + t + 128] = f2b(fmaxf(a1 * inv, 0.f));
}

// ---- pair-XCD swizzle: bn-siblings (bid=2k,2k+1) land on the SAME XCD ----
static __device__ __forceinline__ int pair_swz(int bid, int nwg) {
  const int cpx2 = nwg >> 4;                 // pairs per XCD
  const int pr = bid >> 1, q = bid & 1;
  return (((pr & 7) * cpx2) + (pr >> 3)) * 2 + q;
}

// ---- 128x256 ring-2 GEMM, all-gload_lds staging (geo gather) + row-stats out ----
// Stats: per wave, per row: (sum, sumsq) over its 64 cols -> statsOut[row*16 + 8+bn*4+wn]
__global__ __launch_bounds__(512, 4)
void gemm_geo(const unsigned short* __restrict__ Bt, int Ktot,
              const float* __restrict__ bias,
              unsigned short* __restrict__ C, int ldcE, int ccol0,
              int NS, int NBN,
              const int* __restrict__ pidx,
              const unsigned short* __restrict__ nodeFb,
              const unsigned short* __restrict__ zsrc,
              float2* __restrict__ statsOut) {
  __shared__ __align__(16) unsigned char smem[49152];   // A 2x8K | B 2x16K @16K
  const int tid = threadIdx.x;
  const int lane = tid & 63, w = tid >> 6;
  const int swz = pair_swz(blockIdx.x, gridDim.x);
  const int bm = swz / NBN, bn = swz - bm * NBN;

  const int sslot = (tid & 3) ^ ((tid >> 3) & 3);       // pre-swizzled source k-slot
  const int srow = tid >> 2;                            // 0..127
  const size_t ldbBy = (size_t)Ktot * 2;
  const unsigned char* bG = (const unsigned char*)Bt + (size_t)(bn * 256 + srow) * ldbBy + sslot * 16;

  int pr = bm * 128 + srow;
  int2 so = *(const int2*)(pidx + 2 * pr);
  int b = pr >> 12;
  const unsigned short* nbS = nodeFb + (size_t)((b << 7) + so.x) * NODEF;
  const unsigned short* nbO = nodeFb + (size_t)((b << 7) + so.y) * NODEF;

  auto stage = [&](int s) {
    const int slot = s & 1;
    unsigned char* la = smem + slot * 8192 + w * 1024;
    unsigned char* lb = smem + 16384 + slot * 16384 + w * 1024;
    const int e = s * 32 + sslot * 8;
    uintptr_t sel = (e < NODEF) ? (uintptr_t)(nbS + e)
                  : (e < KGEO)  ? (uintptr_t)(nbO + (e - NODEF))
                                : (uintptr_t)zsrc;
    async_copy16((const void*)sel, la);
    const unsigned char* sb = bG + (size_t)s * 64;
    async_copy16(sb, lb);
    async_copy16(sb + 128 * ldbBy, lb + 8192);
  };

  const int wm = w >> 2, wn = w & 3;                    // 2M x 4N waves, 64x64 each
  const int frow = lane & 15;
  const int colb = (((lane >> 4) ^ ((frow >> 1) & 3)) << 4);
  const int aRowB = (wm * 64 + frow) * 64;
  const int bRowB = (wn * 64 + frow) * 64;

  f32x4 acc[4][4];
#pragma unroll
  for (int m = 0; m < 4; m++)
#pragma unroll
    for (int n = 0; n < 4; n++) acc[m][n] = (f32x4){0.f, 0.f, 0.f, 0.f};

  stage(0); stage(1);
#pragma unroll 1
  for (int s = 0; s < NS; ++s) {
    if (s == NS - 1) asm volatile("s_waitcnt vmcnt(0)" ::: "memory");
    else             asm volatile("s_waitcnt vmcnt(3)" ::: "memory");
    __builtin_amdgcn_s_barrier();
    __builtin_amdgcn_sched_barrier(0);
    const unsigned char* ab = smem + (s & 1) * 8192;
    const unsigned char* bb = smem + 16384 + (s & 1) * 16384;
    bf16x8 af[4];
#pragma unroll
    for (int m = 0; m < 4; m++) af[m] = *(const bf16x8*)(ab + aRowB + m * 1024 + colb);
    __builtin_amdgcn_s_setprio(1);
#pragma unroll
    for (int n = 0; n < 4; n++) {
      bf16x8 bf = *(const bf16x8*)(bb + bRowB + n * 1024 + colb);
#pragma unroll
      for (int m = 0; m < 4; m++)
        acc[m][n] = __builtin_amdgcn_mfma_f32_16x16x32_bf16(af[m], bf, acc[m][n], 0, 0, 0);
    }
    __builtin_amdgcn_s_setprio(0);
    __builtin_amdgcn_sched_barrier(0);
    __builtin_amdgcn_s_barrier();
    __builtin_amdgcn_sched_barrier(0);
    if (s + 2 < NS) stage(s + 2);
  }
  const int rb = bm * 128 + wm * 64 + ((lane >> 4) << 2);
  const int cb = bn * 256 + wn * 64 + frow;
  float bv[4];
#pragma unroll
  for (int n = 0; n < 4; n++) bv[n] = bias[cb + n * 16];
#pragma unroll
  for (int n = 0; n < 4; n++) {
    const int col = cb + n * 16;
#pragma unroll
    for (int m = 0; m < 4; m++)
#pragma unroll
      for (int i = 0; i < 4; i++)
        C[(size_t)(rb + m * 16 + i) * ldcE + ccol0 + col] = f2b(acc[m][n][i] + bv[n]);
  }
  const int slot = 8 + bn * 4 + wn;
#pragma unroll
  for (int m = 0; m < 4; m++)
#pragma unroll
    for (int i = 0; i < 4; i++) {
      float s = 0.f, s2 = 0.f;
#pragma unroll
      for (int n = 0; n < 4; n++) {
        float v = acc[m][n][i] + bv[n];
        s += v; s2 = fmaf(v, v, s2);
      }
#pragma unroll
      for (int off = 1; off <= 8; off <<= 1) { s += __shfl_xor(s, off); s2 += __shfl_xor(s2, off); }
      if (frow == 0) statsOut[(size_t)(rb + m * 16 + i) * 16 + slot] = make_float2(s, s2);
    }
}

// ---- 128x256 ring-2 GEMM, A f32+relu+cvt reg-staged (vis) + row-stats out ----
__global__ __launch_bounds__(512, 4)
void gemm256f3(const float* __restrict__ A,            // f32, lda = 1024
               const unsigned short* __restrict__ Bt,  // [512][1024] bf16
               const float* __restrict__ bias,
               unsigned short* __restrict__ C, int ldcE, int ccol0,
               int NBN, float2* __restrict__ statsOut) {
  constexpr int NS = 32;                               // K=1024 / BK=32
  __shared__ __align__(16) unsigned char smem[49152];  // A 2x8K | B 2x16K @16K
  const int tid = threadIdx.x;
  const int lane = tid & 63, w = tid >> 6;
  const int swz = pair_swz(blockIdx.x, gridDim.x);
  const int bm = swz / NBN, bn = swz - bm * NBN;

  const int sslot = (tid & 3) ^ ((tid >> 3) & 3);
  const int srow = tid >> 2;
  const float* aG = A + (size_t)(bm * 128 + srow) * 1024 + sslot * 8;
  const unsigned char* bG = (const unsigned char*)Bt + (size_t)(bn * 256 + srow) * 2048 + sslot * 16;
  unsigned char* laBase = smem + srow * 64 + (tid & 3) * 16;
  unsigned char* lbBase = smem + 16384 + w * 1024;

  uint4 ra0[2], ra1[2];

  auto issueA = [&](int s, uint4* ra) {
    const float* p0 = aG + (size_t)s * 32;
    ra[0] = *(const uint4*)(p0);
    ra[1] = *(const uint4*)(p0 + 4);
  };
  auto issueB = [&](int s) {
    const int slot = s & 1;
    const unsigned char* sb = bG + (size_t)s * 64;
    async_copy16(sb, lbBase + slot * 16384);
    async_copy16(sb + 128 * 2048, lbBase + slot * 16384 + 8192);
  };
  auto writeA = [&](int s, const uint4* ra) {
    const int slot = s & 1;
    float x0 = fmaxf(__uint_as_float(ra[0].x), 0.f);
    float x1 = fmaxf(__uint_as_float(ra[0].y), 0.f);
    float x2 = fmaxf(__uint_as_float(ra[0].z), 0.f);
    float x3 = fmaxf(__uint_as_float(ra[0].w), 0.f);
    float x4 = fmaxf(__uint_as_float(ra[1].x), 0.f);
    float x5 = fmaxf(__uint_as_float(ra[1].y), 0.f);
    float x6 = fmaxf(__uint_as_float(ra[1].z), 0.f);
    float x7 = fmaxf(__uint_as_float(ra[1].w), 0.f);
    uint4 u;
    u.x = pack2(x0, x1); u.y = pack2(x2, x3);
    u.z = pack2(x4, x5); u.w = pack2(x6, x7);
    *(uint4*)(laBase + slot * 8192) = u;
  };

  const int wm = w >> 2, wn = w & 3;
  const int frow = lane & 15;
  const int colb = (((lane >> 4) ^ ((frow >> 1) & 3)) << 4);
  const int aRowB = (wm * 64 + frow) * 64;
  const int bRowB = (wn * 64 + frow) * 64;

  f32x4 acc[4][4];
#pragma unroll
  for (int m = 0; m < 4; m++)
#pragma unroll
    for (int n = 0; n < 4; n++) acc[m][n] = (f32x4){0.f, 0.f, 0.f, 0.f};

  issueA(0, ra0); issueB(0);
  issueA(1, ra1); issueB(1);

#pragma unroll 1
  for (int s = 0; s < NS; s += 2) {
#pragma unroll
    for (int half = 0; half < 2; half++) {
      const int sc = s + half;
      uint4* raC = half ? ra1 : ra0;
      if (sc == NS - 1) asm volatile("s_waitcnt vmcnt(0)" ::: "memory");
      else              asm volatile("s_waitcnt vmcnt(4)" ::: "memory");
      __builtin_amdgcn_sched_barrier(0);
      writeA(sc, raC);
      if (sc + 2 < NS) issueA(sc + 2, raC);
      asm volatile("s_waitcnt lgkmcnt(0)" ::: "memory");
      __builtin_amdgcn_s_barrier();
      __builtin_amdgcn_sched_barrier(0);
      const unsigned char* ab = smem + (sc & 1) * 8192;
      const unsigned char* bb = smem + 16384 + (sc & 1) * 16384;
      bf16x8 af[4];
#pragma unroll
      for (int m = 0; m < 4; m++) af[m] = *(const bf16x8*)(ab + aRowB + m * 1024 + colb);
      __builtin_amdgcn_s_setprio(1);
#pragma unroll
      for (int n = 0; n < 4; n++) {
        bf16x8 bf = *(const bf16x8*)(bb + bRowB + n * 1024 + colb);
#pragma unroll
        for (int m = 0; m < 4; m++)
          acc[m][n] = __builtin_amdgcn_mfma_f32_16x16x32_bf16(af[m], bf, acc[m][n], 0, 0, 0);
      }
      __builtin_amdgcn_s_setprio(0);
      __builtin_amdgcn_sched_barrier(0);
      __builtin_amdgcn_s_barrier();
      __builtin_amdgcn_sched_barrier(0);
      if (sc + 2 < NS) issueB(sc + 2);
    }
  }
  const int rb = bm * 128 + wm * 64 + ((lane >> 4) << 2);
  const int cb = bn * 256 + wn * 64 + frow;
  float bv[4];
#pragma unroll
  for (int n = 0; n < 4; n++) bv[n] = bias[cb + n * 16];
#pragma unroll
  for (int n = 0; n < 4; n++) {
    const int col = cb + n * 16;
#pragma unroll
    for (int m = 0; m < 4; m++)
#pragma unroll
      for (int i = 0; i < 4; i++)
        C[(size_t)(rb + m * 16 + i) * ldcE + ccol0 + col] = f2b(acc[m][n][i] + bv[n]);
  }
  const int slot = bn * 4 + wn;
#pragma unroll
  for (int m = 0; m < 4; m++)
#pragma unroll
    for (int i = 0; i < 4; i++) {
      float s = 0.f, s2 = 0.f;
#pragma unroll
      for (int n = 0; n < 4; n++) {
        float v = acc[m][n][i] + bv[n];
        s += v; s2 = fmaf(v, v, s2);
      }
#pragma unroll
      for (int off = 1; off <= 8; off <<= 1) { s += __shfl_xor(s, off); s2 += __shfl_xor(s2, off); }
      if (frow == 0) statsOut[(size_t)(rb + m * 16 + i) * 16 + slot] = make_float2(s, s2);
    }
}

// ---- 128x256 ring-2 GEMM, FUSED LayerNorm+ReLU A-staging (fus) + stats2 out ----
__global__ __launch_bounds__(512, 4)
void gemm_fusLN(const unsigned short* __restrict__ A,   // fused bf16 [M][1024]
                const unsigned short* __restrict__ Bt,  // wT_fus [512][1024]
                const float2* __restrict__ statsIn,     // [M][16] partial (s,s2)
                const float* __restrict__ lng, const float* __restrict__ lnb,
                const float* __restrict__ bias,
                unsigned short* __restrict__ C,         // fused2 [M][512]
                int NBN, float2* __restrict__ statsOut) {
  constexpr int NS = 32;
  __shared__ __align__(16) unsigned char smem[57344];
  const int tid = threadIdx.x;
  const int lane = tid & 63, w = tid >> 6;
  const int swz = pair_swz(blockIdx.x, gridDim.x);
  const int bm = swz / NBN, bn = swz - bm * NBN;

  const int sslot = (tid & 3) ^ ((tid >> 3) & 3);
  const int srow = tid >> 2;
  const unsigned short* aG = A + (size_t)(bm * 128 + srow) * 1024 + sslot * 8;
  const unsigned char* bG = (const unsigned char*)Bt + (size_t)(bn * 256 + srow) * 2048 + sslot * 16;
  unsigned char* laBase = smem + srow * 64 + (tid & 3) * 16;
  unsigned char* lbBase = smem + 16384 + w * 1024;

  {
    const float* src = (w < 4) ? (lng + w * 256 + lane * 4)
                               : (lnb + (w - 4) * 256 + lane * 4);
    unsigned char* dst = smem + 49152 + w * 1024;
    async_copy16(src, dst);
  }
  asm volatile("s_waitcnt vmcnt(0)" ::: "memory");
  __builtin_amdgcn_s_barrier();

  float ssum = 0.f, ssq = 0.f;
  {
    const float2* sp = statsIn + (size_t)(bm * 128 + srow) * 16;
#pragma unroll
    for (int j = 0; j < 16; j++) { float2 p = sp[j]; ssum += p.x; ssq += p.y; }
  }
  const float mu = ssum * (1.f / 1024.f);
  const float rs = rsqrtf(ssq * (1.f / 1024.f) - mu * mu + 1e-5f);
  const float* gl = (const float*)(smem + 49152);
  const float* bl = (const float*)(smem + 53248);

  uint4 ra0, ra1;

  auto issueA = [&](int s, uint4* ra) {
    *ra = *(const uint4*)(aG + (size_t)s * 32);
  };
  auto issueB = [&](int s) {
    const int slot = s & 1;
    const unsigned char* sb = bG + (size_t)s * 64;
    async_copy16(sb, lbBase + slot * 16384);
    async_copy16(sb + 128 * 2048, lbBase + slot * 16384 + 8192);
  };
  auto writeA = [&](int s, const uint4* ra) {
    const int slot = s & 1;
    const int k0 = s * 32 + sslot * 8;
    float x[8]; unpack8(*ra, x);
    float4 g0 = *(const float4*)(gl + k0), g1 = *(const float4*)(gl + k0 + 4);
    float4 t0 = *(const float4*)(bl + k0), t1 = *(const float4*)(bl + k0 + 4);
    float y0 = fmaxf(fmaf((x[0] - mu) * rs, g0.x, t0.x), 0.f);
    float y1 = fmaxf(fmaf((x[1] - mu) * rs, g0.y, t0.y), 0.f);
    float y2 = fmaxf(fmaf((x[2] - mu) * rs, g0.z, t0.z), 0.f);
    float y3 = fmaxf(fmaf((x[3] - mu) * rs, g0.w, t0.w), 0.f);
    float y4 = fmaxf(fmaf((x[4] - mu) * rs, g1.x, t1.x), 0.f);
    float y5 = fmaxf(fmaf((x[5] - mu) * rs, g1.y, t1.y), 0.f);
    float y6 = fmaxf(fmaf((x[6] - mu) * rs, g1.z, t1.z), 0.f);
    float y7 = fmaxf(fmaf((x[7] - mu) * rs, g1.w, t1.w), 0.f);
    uint4 u;
    u.x = pack2(y0, y1); u.y = pack2(y2, y3);
    u.z = pack2(y4, y5); u.w = pack2(y6, y7);
    *(uint4*)(laBase + slot * 8192) = u;
  };

  const int wm = w >> 2, wn = w & 3;
  const int frow = lane & 15;
  const int colb = (((lane >> 4) ^ ((frow >> 1) & 3)) << 4);
  const int aRowB = (wm * 64 + frow) * 64;
  const int bRowB = (wn * 64 + frow) * 64;

  f32x4 acc[4][4];
#pragma unroll
  for (int m = 0; m < 4; m++)
#pragma unroll
    for (int n = 0; n < 4; n++) acc[m][n] = (f32x4){0.f, 0.f, 0.f, 0.f};

  issueA(0, &ra0); issueB(0);
  issueA(1, &ra1); issueB(1);

#pragma unroll 1
  for (int s = 0; s < NS; s += 2) {
#pragma unroll
    for (int half = 0; half < 2; half++) {
      const int sc = s + half;
      uint4* raC = half ? &ra1 : &ra0;
      if (sc == NS - 1) asm volatile("s_waitcnt vmcnt(0)" ::: "memory");
      else              asm volatile("s_waitcnt vmcnt(3)" ::: "memory");
      __builtin_amdgcn_sched_barrier(0);
      writeA(sc, raC);
      if (sc + 2 < NS) issueA(sc + 2, raC);
      asm volatile("s_waitcnt lgkmcnt(0)" ::: "memory");
      __builtin_amdgcn_s_barrier();
      __builtin_amdgcn_sched_barrier(0);
      const unsigned char* ab = smem + (sc & 1) * 8192;
      const unsigned char* bb = smem + 16384 + (sc & 1) * 16384;
      bf16x8 af[4];
#pragma unroll
      for (int m = 0; m < 4; m++) af[m] = *(const bf16x8*)(ab + aRowB + m * 1024 + colb);
      __builtin_amdgcn_s_setprio(1);
#pragma unroll
      for (int n = 0; n < 4; n++) {
        bf16x8 bf = *(const bf16x8*)(bb + bRowB + n * 1024 + colb);
#pragma unroll
        for (int m = 0; m < 4; m++)
          acc[m][n] = __builtin_amdgcn_mfma_f32_16x16x32_bf16(af[m], bf, acc[m][n], 0, 0, 0);
      }
      __builtin_amdgcn_s_setprio(0);
      __builtin_amdgcn_sched_barrier(0);
      __builtin_amdgcn_s_barrier();
      __builtin_amdgcn_sched_barrier(0);
      if (sc + 2 < NS) issueB(sc + 2);
    }
  }
  const int rb = bm * 128 + wm * 64 + ((lane >> 4) << 2);
  const int cb = bn * 256 + wn * 64 + frow;
  float bv[4];
#pragma unroll
  for (int n = 0; n < 4; n++) bv[n] = bias[cb + n * 16];
#pragma unroll
  for (int n = 0; n < 4; n++) {
    const int col = cb + n * 16;
#pragma unroll
    for (int m = 0; m < 4; m++)
#pragma unroll
      for (int i = 0; i < 4; i++)
        C[(size_t)(rb + m * 16 + i) * 512 + col] = f2b(acc[m][n][i] + bv[n]);
  }
  const int slot = bn * 4 + wn;
#pragma unroll
  for (int m = 0; m < 4; m++)
#pragma unroll
    for (int i = 0; i < 4; i++) {
      float s = 0.f, s2 = 0.f;
#pragma unroll
      for (int n = 0; n < 4; n++) {
        float v = acc[m][n][i] + bv[n];
        s += v; s2 = fmaf(v, v, s2);
      }
#pragma unroll
      for (int off = 1; off <= 8; off <<= 1) { s += __shfl_xor(s, off); s2 += __shfl_xor(s2, off); }
      if (frow == 0) statsOut[(size_t)(rb + m * 16 + i) * 8 + slot] = make_float2(s, s2);
    }
}

// ---- 128x128 ring-2 cls GEMM with FUSED LN+ReLU A-staging + score scatter ----
__global__ __launch_bounds__(512, 4)
void gemm_clsLN(const unsigned short* __restrict__ A,   // fused2 bf16 [M][512]
                const unsigned short* __restrict__ Bt,  // wT_cls [128][512]
                const float2* __restrict__ statsIn,     // [M][8] partial (s,s2)
                const float* __restrict__ lng, const float* __restrict__ lnb,
                const float* __restrict__ bias,
                float* __restrict__ C,                  // logits [M][50]
                const int* __restrict__ pidx,
                unsigned long long* __restrict__ scat) {
  constexpr int NS = 16;
  __shared__ __align__(16) unsigned char smem[36864];
  const int tid = threadIdx.x;
  const int lane = tid & 63, w = tid >> 6;
  const int cpx = gridDim.x >> 3;
  const int bm = (blockIdx.x & 7) * cpx + (blockIdx.x >> 3);

  const int sslot = (tid & 3) ^ ((tid >> 3) & 3);
  const int srow = tid >> 2;
  const unsigned short* aG = A + (size_t)(bm * 128 + srow) * 512 + sslot * 8;
  const unsigned char* bG = (const unsigned char*)Bt + (size_t)srow * 1024 + sslot * 16;
  unsigned char* laBase = smem + srow * 64 + (tid & 3) * 16;
  unsigned char* lbBase = smem + 16384 + w * 1024;

  if (w < 4) {
    const float* src = (w < 2) ? (lng + w * 256 + lane * 4)
                               : (lnb + (w - 2) * 256 + lane * 4);
    unsigned char* dst = smem + 32768 + ((w < 2) ? w * 1024 : 2048 + (w - 2) * 1024);
    async_copy16(src, dst);
  }
  asm volatile("s_waitcnt vmcnt(0)" ::: "memory");
  __builtin_amdgcn_s_barrier();

  float ssum = 0.f, ssq = 0.f;
  {
    const float2* sp = statsIn + (size_t)(bm * 128 + srow) * 8;
#pragma unroll
    for (int j = 0; j < 8; j++) { float2 p = sp[j]; ssum += p.x; ssq += p.y; }
  }
  const float mu = ssum * (1.f / 512.f);
  const float rs = rsqrtf(ssq * (1.f / 512.f) - mu * mu + 1e-5f);
  const float* gl = (const float*)(smem + 32768);
  const float* bl = (const float*)(smem + 34816);

  uint4 ra0, ra1;
  auto issueA = [&](int s, uint4* ra) { *ra = *(const uint4*)(aG + (size_t)s * 32); };
  auto issueB = [&](int s) {
    async_copy16(bG + (size_t)s * 64, lbBase + (s & 1) * 8192);
  };
  auto writeA = [&](int s, const uint4* ra) {
    const int slot = s & 1;
    const int k0 = s * 32 + sslot * 8;
    float x[8]; unpack8(*ra, x);
    float4 g0 = *(const float4*)(gl + k0), g1 = *(const float4*)(gl + k0 + 4);
    float4 t0 = *(const float4*)(bl + k0), t1 = *(const float4*)(bl + k0 + 4);
    float y0 = fmaxf(fmaf((x[0] - mu) * rs, g0.x, t0.x), 0.f);
    float y1 = fmaxf(fmaf((x[1] - mu) * rs, g0.y, t0.y), 0.f);
    float y2 = fmaxf(fmaf((x[2] - mu) * rs, g0.z, t0.z), 0.f);
    float y3 = fmaxf(fmaf((x[3] - mu) * rs, g0.w, t0.w), 0.f);
    float y4 = fmaxf(fmaf((x[4] - mu) * rs, g1.x, t1.x), 0.f);
    float y5 = fmaxf(fmaf((x[5] - mu) * rs, g1.y, t1.y), 0.f);
    float y6 = fmaxf(fmaf((x[6] - mu) * rs, g1.z, t1.z), 0.f);
    float y7 = fmaxf(fmaf((x[7] - mu) * rs, g1.w, t1.w), 0.f);
    uint4 u;
    u.x = pack2(y0, y1); u.y = pack2(y2, y3);
    u.z = pack2(y4, y5); u.w = pack2(y6, y7);
    *(uint4*)(laBase + slot * 8192) = u;
  };

  const int wm = w >> 1, wn = w & 1;
  const int frow = lane & 15;
  const int colb = (((lane >> 4) ^ ((frow >> 1) & 3)) << 4);
  const int aRowB = (wm * 32 + frow) * 64;
  const int bRowB = (wn * 64 + frow) * 64;

  f32x4 acc[2][4];
#pragma unroll
  for (int m = 0; m < 2; m++)
#pragma unroll
    for (int n = 0; n < 4; n++) acc[m][n] = (f32x4){0.f, 0.f, 0.f, 0.f};

  issueA(0, &ra0); issueB(0);
  issueA(1, &ra1); issueB(1);

#pragma unroll 1
  for (int s = 0; s < NS; s += 2) {
#pragma unroll
    for (int half = 0; half < 2; half++) {
      const int sc = s + half;
      uint4* raC = half ? &ra1 : &ra0;
      if (sc == NS - 1) asm volatile("s_waitcnt vmcnt(0)" ::: "memory");
      else              asm volatile("s_waitcnt vmcnt(2)" ::: "memory");
      __builtin_amdgcn_sched_barrier(0);
      writeA(sc, raC);
      if (sc + 2 < NS) issueA(sc + 2, raC);
      asm volatile("s_waitcnt lgkmcnt(0)" ::: "memory");
      __builtin_amdgcn_s_barrier();
      __builtin_amdgcn_sched_barrier(0);
      const unsigned char* ab = smem + (sc & 1) * 8192;
      const unsigned char* bb = smem + 16384 + (sc & 1) * 8192;
      bf16x8 af[2];
#pragma unroll
      for (int m = 0; m < 2; m++) af[m] = *(const bf16x8*)(ab + aRowB + m * 1024 + colb);
      __builtin_amdgcn_s_setprio(1);
#pragma unroll
      for (int n = 0; n < 4; n++) {
        bf16x8 bf = *(const bf16x8*)(bb + bRowB + n * 1024 + colb);
#pragma unroll
        for (int m = 0; m < 2; m++)
          acc[m][n] = __builtin_amdgcn_mfma_f32_16x16x32_bf16(af[m], bf, acc[m][n], 0, 0, 0);
      }
      __builtin_amdgcn_s_setprio(0);
      __builtin_amdgcn_sched_barrier(0);
      __builtin_amdgcn_s_barrier();
      __builtin_amdgcn_sched_barrier(0);
      if (sc + 2 < NS) issueB(sc + 2);
    }
  }
  const int rb = bm * 128 + wm * 32 + ((lane >> 4) << 2);
  const int cbl = wn * 64 + frow;
#pragma unroll
  for (int n = 0; n < 4; n++) {
    const int col = cbl + n * 16;
    const float bv = (col < OUTC) ? bias[col] : 0.f;
#pragma unroll
    for (int m = 0; m < 2; m++)
#pragma unroll
      for (int i = 0; i < 4; i++) {
        const int row = rb + m * 16 + i;
        if (col < OUTC) C[(size_t)row * OUTC + col] = acc[m][n][i] + bv;
      }
  }
  if (wn == 0) {
#pragma unroll
    for (int m = 0; m < 2; m++)
#pragma unroll
      for (int i = 0; i < 4; i++) {
        float mx = -1e30f;
#pragma unroll
        for (int n = 0; n < 4; n++) {
          const int col = n * 16 + frow;
          float v = acc[m][n][i] + ((col < OUTC) ? bias[col] : 0.f);
          if (col < OUTC) mx = fmaxf(mx, v);
        }
        mx = fmaxf(mx, __shfl_xor(mx, 1));
        mx = fmaxf(mx, __shfl_xor(mx, 2));
        mx = fmaxf(mx, __shfl_xor(mx, 4));
        mx = fmaxf(mx, __shfl_xor(mx, 8));
        if (frow == 0) {
          const int row = rb + m * 16 + i;
          float sc = 1.f / (1.f + expf(-mx));
          int b = row >> 12, p = row & 4095;
          int s = pidx[2 * row], o = pidx[2 * row + 1];
          unsigned long long key = (((unsigned long long)(p + 1)) << 32) |
                                   (unsigned long long)__float_as_uint(sc);
          atomicMax(&scat[((size_t)(b * N_ + s) << 7) + o], key);
        }
      }
  }
}

__global__ void relmat_kernel(const unsigned long long* __restrict__ scat, float* __restrict__ out) {
  int i = blockIdx.x * blockDim.x + threadIdx.x;
  if (i >= B_ * N_ * N_) return;
  unsigned long long v = scat[i];
  out[i] = v ? __uint_as_float((unsigned)(v & 0xffffffffu)) : 0.f;
}

extern "C" void kernel_launch(void* const* d_in, const int* in_sizes, int n_in,
                              void* d_out, int out_size, void* d_ws, size_t ws_size,
                              hipStream_t stream) {
  const float* visual_feat = (const float*)d_in[0];
  const float* box_info    = (const float*)d_in[1];
  const float* pred_logits = (const float*)d_in[2];
  const int*   pair_idx    = (const int*)d_in[3];
  const float* obj_sem_w   = (const float*)d_in[4];
  const float* pos_w1 = (const float*)d_in[5];
  const float* pos_b1 = (const float*)d_in[6];
  const float* pos_w2 = (const float*)d_in[7];
  const float* pos_b2 = (const float*)d_in[8];
  const float* vis_w  = (const float*)d_in[9];
  const float* vis_b  = (const float*)d_in[10];
  const float* geo_w  = (const float*)d_in[11];
  const float* geo_b  = (const float*)d_in[12];
  const float* fus_g  = (const float*)d_in[13];
  const float* fus_bt = (const float*)d_in[14];
  const float* fus_w  = (const float*)d_in[15];
  const float* fus_b  = (const float*)d_in[16];
  const float* cls_g  = (const float*)d_in[17];
  const float* cls_bt = (const float*)d_in[18];
  const float* cls_w  = (const float*)d_in[19];
  const float* cls_b  = (const float*)d_in[20];

  char* ws = (char*)d_ws;
  size_t off = 0;
  auto alloc = [&](size_t bytes) { char* p = ws + off; off += (bytes + 255) & ~(size_t)255; return p; };
  unsigned short* fused = (unsigned short*)alloc((size_t)M_ * 1024 * 2);      // 134 MB
  unsigned short* fused2 = (unsigned short*)alloc((size_t)M_ * 512 * 2);      // 67 MB
  unsigned short* nodeFb = (unsigned short*)alloc((size_t)B_ * N_ * NODEF * 2);
  unsigned short* wT_vis = (unsigned short*)alloc((size_t)512 * 1024 * 2);
  unsigned short* wT_geo = (unsigned short*)alloc((size_t)512 * KGEOP * 2);
  unsigned short* wT_fus = (unsigned short*)alloc((size_t)512 * 1024 * 2);
  unsigned short* wT_cls = (unsigned short*)alloc((size_t)128 * 512 * 2);
  unsigned long long* scat = (unsigned long long*)alloc((size_t)B_ * N_ * N_ * 8);
  float2* statsP1 = (float2*)alloc((size_t)M_ * 16 * 8);                      // 8 MB
  float2* statsP2 = (float2*)alloc((size_t)M_ * 8 * 8);                       // 4 MB

  float* out_logits = (float*)d_out;
  float* out_rel = out_logits + (size_t)M_ * OUTC;

  prep_kernel<<<dim3((PREP_TOT + 255) / 256), 256, 0, stream>>>(
      (uint4*)scat, vis_w, wT_vis, geo_w, wT_geo, fus_w, wT_fus, cls_w, wT_cls);
  node_kernel<<<dim3(B_ * N_), 128, 0, stream>>>(box_info, pred_logits, obj_sem_w,
                                                 pos_w1, pos_b1, pos_w2, pos_b2, nodeFb);
  // geo: gather GEMM -> fused[:,512:] + partial row stats (slots 8..15)
  gemm_geo<<<dim3(1024), 512, 0, stream>>>(wT_geo, KGEOP, geo_b,
                                           fused, 1024, 512, KGEOP / 32, 2,
                                           pair_idx, nodeFb, (const unsigned short*)scat,
                                           statsP1);
  // vis: f32+relu GEMM -> fused[:,0:512] + partial row stats (slots 0..7)
  gemm256f3<<<dim3(1024), 512, 0, stream>>>(visual_feat, wT_vis, vis_b,
                                            fused, 1024, 0, 2, statsP1);
  // fus: LN(stats combine)+relu in A-staging -> fused2 + partial stats2 (8 slots)
  gemm_fusLN<<<dim3(1024), 512, 0, stream>>>(fused, wT_fus, statsP1, fus_g, fus_bt,
                                             fus_b, fused2, 2, statsP2);
  // cls: LN(stats2)+relu in A-staging -> logits + fused score scatter
  gemm_clsLN<<<dim3(512), 512, 0, stream>>>(fused2, wT_cls, statsP2, cls_g, cls_bt,
                                            cls_b, out_logits, pair_idx, scat);
  relmat_kernel<<<dim3((B_ * N_ * N_) / 256), 256, 0, stream>>>(scat, out_rel);
}

// Round 21
// 372.798 us; speedup vs baseline: 1.0859x; 1.0024x over previous
//
#include <hip/hip_runtime.h>
#include <cstdint>

#define B_    16
#define N_    128
#define P_    4096
#define M_    65536     // B_*P_
#define DIN   1024
#define DHID  512
#define DGEO  128
#define DEMB  200
#define NODEF 328       // DGEO + DEMB
#define NOBJ  151
#define OUTC  50
#define KGEO  656
#define KGEOP 672       // geo K padded to multiple of 32 (ring BK=32)

typedef __attribute__((ext_vector_type(8))) short bf16x8;
typedef __attribute__((ext_vector_type(4))) float f32x4;

typedef __attribute__((address_space(3))) unsigned char lds_u8;
typedef __attribute__((address_space(1))) unsigned char glb_u8;

static __device__ __forceinline__ void async_copy16(const void* g, void* l) {
  __builtin_amdgcn_global_load_lds((const glb_u8*)g, (lds_u8*)l, 16, 0, 0);
}

static __device__ __forceinline__ unsigned short f2b(float f) {
  union { float f; unsigned u; } v; v.f = f;
  unsigned r = v.u + 0x7fffu + ((v.u >> 16) & 1u);
  return (unsigned short)(r >> 16);
}
static __device__ __forceinline__ float b2f(unsigned short b) {
  union { unsigned u; float f; } v; v.u = ((unsigned)b) << 16;
  return v.f;
}
static __device__ __forceinline__ unsigned pack2(float a, float b) {
  return (unsigned)f2b(a) | ((unsigned)f2b(b) << 16);
}
static __device__ __forceinline__ void unpack8(uint4 raw, float* x) {
  x[0] = b2f(raw.x & 0xffffu); x[1] = b2f(raw.x >> 16);
  x[2] = b2f(raw.y & 0xffffu); x[3] = b2f(raw.y >> 16);
  x[4] = b2f(raw.z & 0xffffu); x[5] = b2f(raw.z >> 16);
  x[6] = b2f(raw.w & 0xffffu); x[7] = b2f(raw.w >> 16);
}

// ---- merged prologue: zero scat + all 4 weight transposes in one launch ----
#define ZN   131072                    // scat zero, uint4 count (2 MB)
#define TV   (512 * 1024)              // wT_vis elems
#define TG   (512 * KGEOP)             // wT_geo elems
#define TF   (512 * 1024)              // wT_fus elems
#define TC   (128 * 512)               // wT_cls elems
#define PREP_TOT (ZN + TV + TG + TF + TC)
__global__ __launch_bounds__(256)
void prep_kernel(uint4* __restrict__ scat,
                 const float* __restrict__ vis_w, unsigned short* __restrict__ wT_vis,
                 const float* __restrict__ geo_w, unsigned short* __restrict__ wT_geo,
                 const float* __restrict__ fus_w, unsigned short* __restrict__ wT_fus,
                 const float* __restrict__ cls_w, unsigned short* __restrict__ wT_cls) {
  int idx = blockIdx.x * 256 + threadIdx.x;
  if (idx < ZN) { scat[idx] = make_uint4(0, 0, 0, 0); return; }
  idx -= ZN;
  if (idx < TV) {
    int n = idx >> 10, k = idx & 1023;
    wT_vis[idx] = f2b(vis_w[(size_t)k * 512 + n]);
    return;
  }
  idx -= TV;
  if (idx < TG) {
    int n = idx / KGEOP, k = idx - n * KGEOP;
    wT_geo[idx] = (k < KGEO) ? f2b(geo_w[(size_t)k * 512 + n]) : 0;
    return;
  }
  idx -= TG;
  if (idx < TF) {
    int n = idx >> 10, k = idx & 1023;
    wT_fus[idx] = f2b(fus_w[(size_t)k * 512 + n]);
    return;
  }
  idx -= TF;
  if (idx < TC) {
    int n = idx >> 9, k = idx & 511;
    wT_cls[idx] = (n < OUTC) ? f2b(cls_w[(size_t)k * OUTC + n]) : 0;
  }
}

// ---- per-node features (relu'd, bf16): nodeFb[node] = [relu(pos)(128), relu(sem)(200)] ----
__global__ __launch_bounds__(128)
void node_kernel(const float* __restrict__ box, const float* __restrict__ plog,
                 const float* __restrict__ semw,
                 const float* __restrict__ w1, const float* __restrict__ b1,
                 const float* __restrict__ w2, const float* __restrict__ b2,
                 unsigned short* __restrict__ nodeFb) {
  const int node = blockIdx.x;
  const int t = threadIdx.x;
  __shared__ float sBox[9];
  __shared__ float sH[128];
  __shared__ float sE[NOBJ];
  __shared__ float sRed[4];
  if (t < 9) sBox[t] = box[node * 9 + t];
  float l0 = (t < NOBJ) ? plog[node * NOBJ + t] : -1e30f;
  float l1 = (t + 128 < NOBJ) ? plog[node * NOBJ + t + 128] : -1e30f;
  __syncthreads();
  float h = b1[t];
#pragma unroll
  for (int i = 0; i < 9; i++) h = fmaf(sBox[i], w1[i * 128 + t], h);
  h = fmaxf(h, 0.f);
  sH[t] = h;
  float mx = fmaxf(l0, l1);
#pragma unroll
  for (int off = 32; off >= 1; off >>= 1) mx = fmaxf(mx, __shfl_xor(mx, off));
  if ((t & 63) == 0) sRed[t >> 6] = mx;
  __syncthreads();
  mx = fmaxf(sRed[0], sRed[1]);
  float e0 = (t < NOBJ) ? expf(l0 - mx) : 0.f;
  float e1 = (t + 128 < NOBJ) ? expf(l1 - mx) : 0.f;
  if (t < NOBJ) sE[t] = e0;
  if (t + 128 < NOBJ) sE[t + 128] = e1;
  float sm = e0 + e1;
#pragma unroll
  for (int off = 32; off >= 1; off >>= 1) sm += __shfl_xor(sm, off);
  if ((t & 63) == 0) sRed[2 + (t >> 6)] = sm;
  __syncthreads();
  const float inv = 1.f / (sRed[2] + sRed[3]);
  float pv = b2[t];
  for (int i = 0; i < 128; i++) pv = fmaf(sH[i], w2[i * 128 + t], pv);
  nodeFb[(size_t)node * NODEF + t] = f2b(fmaxf(pv, 0.f));
  float a0 = 0.f, a1 = 0.f;
  const int d1 = (t + 128 < DEMB) ? (t + 128) : 0;
  for (int i = 0; i < NOBJ; i++) {
    float e = sE[i];
    a0 = fmaf(e, semw[i * DEMB + t], a0);
    a1 = fmaf(e, semw[i * DEMB + d1], a1);
  }
  nodeFb[(size_t)node * NODEF + 128 + t] = f2b(fmaxf(a0 * inv, 0.f));
  if (t + 128 < DEMB) nodeFb[(size_t)node * NODEF + 128 + t + 128] = f2b(fmaxf(a1 * inv, 0.f));
}

// ---- pair-XCD swizzle: bn-siblings (bid=2k,2k+1) land on the SAME XCD ----
static __device__ __forceinline__ int pair_swz(int bid, int nwg) {
  const int cpx2 = nwg >> 4;                 // pairs per XCD
  const int pr = bid >> 1, q = bid & 1;
  return (((pr & 7) * cpx2) + (pr >> 3)) * 2 + q;
}

// ---- 128x256 ring-2 GEMM, all-gload_lds staging (geo gather) + row-stats out ----
// Stats: per wave, per row: (sum, sumsq) over its 64 cols -> statsOut[row*16 + 8+bn*4+wn]
__global__ __launch_bounds__(512, 4)
void gemm_geo(const unsigned short* __restrict__ Bt, int Ktot,
              const float* __restrict__ bias,
              unsigned short* __restrict__ C, int ldcE, int ccol0,
              int NS, int NBN,
              const int* __restrict__ pidx,
              const unsigned short* __restrict__ nodeFb,
              const unsigned short* __restrict__ zsrc,
              float2* __restrict__ statsOut) {
  __shared__ __align__(16) unsigned char smem[49152];   // A 2x8K | B 2x16K @16K
  const int tid = threadIdx.x;
  const int lane = tid & 63, w = tid >> 6;
  const int swz = pair_swz(blockIdx.x, gridDim.x);
  const int bm = swz / NBN, bn = swz - bm * NBN;

  const int sslot = (tid & 3) ^ ((tid >> 3) & 3);       // pre-swizzled source k-slot
  const int srow = tid >> 2;                            // 0..127
  const size_t ldbBy = (size_t)Ktot * 2;
  const unsigned char* bG = (const unsigned char*)Bt + (size_t)(bn * 256 + srow) * ldbBy + sslot * 16;

  int pr = bm * 128 + srow;
  int2 so = *(const int2*)(pidx + 2 * pr);
  int b = pr >> 12;
  const unsigned short* nbS = nodeFb + (size_t)((b << 7) + so.x) * NODEF;
  const unsigned short* nbO = nodeFb + (size_t)((b << 7) + so.y) * NODEF;

  auto stage = [&](int s) {
    const int slot = s & 1;
    unsigned char* la = smem + slot * 8192 + w * 1024;
    unsigned char* lb = smem + 16384 + slot * 16384 + w * 1024;
    const int e = s * 32 + sslot * 8;
    uintptr_t sel = (e < NODEF) ? (uintptr_t)(nbS + e)
                  : (e < KGEO)  ? (uintptr_t)(nbO + (e - NODEF))
                                : (uintptr_t)zsrc;
    async_copy16((const void*)sel, la);
    const unsigned char* sb = bG + (size_t)s * 64;
    async_copy16(sb, lb);
    async_copy16(sb + 128 * ldbBy, lb + 8192);
  };

  const int wm = w >> 2, wn = w & 3;                    // 2M x 4N waves, 64x64 each
  const int frow = lane & 15;
  const int colb = (((lane >> 4) ^ ((frow >> 1) & 3)) << 4);
  const int aRowB = (wm * 64 + frow) * 64;
  const int bRowB = (wn * 64 + frow) * 64;

  f32x4 acc[4][4];
#pragma unroll
  for (int m = 0; m < 4; m++)
#pragma unroll
    for (int n = 0; n < 4; n++) acc[m][n] = (f32x4){0.f, 0.f, 0.f, 0.f};

  stage(0); stage(1);
#pragma unroll 1
  for (int s = 0; s < NS; ++s) {
    if (s == NS - 1) asm volatile("s_waitcnt vmcnt(0)" ::: "memory");
    else             asm volatile("s_waitcnt vmcnt(3)" ::: "memory");
    __builtin_amdgcn_s_barrier();
    __builtin_amdgcn_sched_barrier(0);
    const unsigned char* ab = smem + (s & 1) * 8192;
    const unsigned char* bb = smem + 16384 + (s & 1) * 16384;
    bf16x8 af[4];
#pragma unroll
    for (int m = 0; m < 4; m++) af[m] = *(const bf16x8*)(ab + aRowB + m * 1024 + colb);
    __builtin_amdgcn_s_setprio(1);
#pragma unroll
    for (int n = 0; n < 4; n++) {
      bf16x8 bf = *(const bf16x8*)(bb + bRowB + n * 1024 + colb);
#pragma unroll
      for (int m = 0; m < 4; m++)
        acc[m][n] = __builtin_amdgcn_mfma_f32_16x16x32_bf16(af[m], bf, acc[m][n], 0, 0, 0);
    }
    __builtin_amdgcn_s_setprio(0);
    __builtin_amdgcn_sched_barrier(0);
    __builtin_amdgcn_s_barrier();
    __builtin_amdgcn_sched_barrier(0);
    if (s + 2 < NS) stage(s + 2);
  }
  const int rb = bm * 128 + wm * 64 + ((lane >> 4) << 2);
  const int cb = bn * 256 + wn * 64 + frow;
  float bv[4];
#pragma unroll
  for (int n = 0; n < 4; n++) bv[n] = bias[cb + n * 16];
#pragma unroll
  for (int n = 0; n < 4; n++) {
    const int col = cb + n * 16;
#pragma unroll
    for (int m = 0; m < 4; m++)
#pragma unroll
      for (int i = 0; i < 4; i++)
        C[(size_t)(rb + m * 16 + i) * ldcE + ccol0 + col] = f2b(acc[m][n][i] + bv[n]);
  }
  const int slot = 8 + bn * 4 + wn;
#pragma unroll
  for (int m = 0; m < 4; m++)
#pragma unroll
    for (int i = 0; i < 4; i++) {
      float s = 0.f, s2 = 0.f;
#pragma unroll
      for (int n = 0; n < 4; n++) {
        float v = acc[m][n][i] + bv[n];
        s += v; s2 = fmaf(v, v, s2);
      }
#pragma unroll
      for (int off = 1; off <= 8; off <<= 1) { s += __shfl_xor(s, off); s2 += __shfl_xor(s2, off); }
      if (frow == 0) statsOut[(size_t)(rb + m * 16 + i) * 16 + slot] = make_float2(s, s2);
    }
}

// ---- 128x256 ring-2 GEMM, A f32+relu+cvt reg-staged (vis) + row-stats out ----
__global__ __launch_bounds__(512, 4)
void gemm256f3(const float* __restrict__ A,            // f32, lda = 1024
               const unsigned short* __restrict__ Bt,  // [512][1024] bf16
               const float* __restrict__ bias,
               unsigned short* __restrict__ C, int ldcE, int ccol0,
               int NBN, float2* __restrict__ statsOut) {
  constexpr int NS = 32;                               // K=1024 / BK=32
  __shared__ __align__(16) unsigned char smem[49152];  // A 2x8K | B 2x16K @16K
  const int tid = threadIdx.x;
  const int lane = tid & 63, w = tid >> 6;
  const int swz = pair_swz(blockIdx.x, gridDim.x);
  const int bm = swz / NBN, bn = swz - bm * NBN;

  const int sslot = (tid & 3) ^ ((tid >> 3) & 3);
  const int srow = tid >> 2;
  const float* aG = A + (size_t)(bm * 128 + srow) * 1024 + sslot * 8;
  const unsigned char* bG = (const unsigned char*)Bt + (size_t)(bn * 256 + srow) * 2048 + sslot * 16;
  unsigned char* laBase = smem + srow * 64 + (tid & 3) * 16;
  unsigned char* lbBase = smem + 16384 + w * 1024;

  uint4 ra0[2], ra1[2];

  auto issueA = [&](int s, uint4* ra) {
    const float* p0 = aG + (size_t)s * 32;
    ra[0] = *(const uint4*)(p0);
    ra[1] = *(const uint4*)(p0 + 4);
  };
  auto issueB = [&](int s) {
    const int slot = s & 1;
    const unsigned char* sb = bG + (size_t)s * 64;
    async_copy16(sb, lbBase + slot * 16384);
    async_copy16(sb + 128 * 2048, lbBase + slot * 16384 + 8192);
  };
  auto writeA = [&](int s, const uint4* ra) {
    const int slot = s & 1;
    float x0 = fmaxf(__uint_as_float(ra[0].x), 0.f);
    float x1 = fmaxf(__uint_as_float(ra[0].y), 0.f);
    float x2 = fmaxf(__uint_as_float(ra[0].z), 0.f);
    float x3 = fmaxf(__uint_as_float(ra[0].w), 0.f);
    float x4 = fmaxf(__uint_as_float(ra[1].x), 0.f);
    float x5 = fmaxf(__uint_as_float(ra[1].y), 0.f);
    float x6 = fmaxf(__uint_as_float(ra[1].z), 0.f);
    float x7 = fmaxf(__uint_as_float(ra[1].w), 0.f);
    uint4 u;
    u.x = pack2(x0, x1); u.y = pack2(x2, x3);
    u.z = pack2(x4, x5); u.w = pack2(x6, x7);
    *(uint4*)(laBase + slot * 8192) = u;
  };

  const int wm = w >> 2, wn = w & 3;
  const int frow = lane & 15;
  const int colb = (((lane >> 4) ^ ((frow >> 1) & 3)) << 4);
  const int aRowB = (wm * 64 + frow) * 64;
  const int bRowB = (wn * 64 + frow) * 64;

  f32x4 acc[4][4];
#pragma unroll
  for (int m = 0; m < 4; m++)
#pragma unroll
    for (int n = 0; n < 4; n++) acc[m][n] = (f32x4){0.f, 0.f, 0.f, 0.f};

  issueA(0, ra0); issueB(0);
  issueA(1, ra1); issueB(1);

#pragma unroll 1
  for (int s = 0; s < NS; s += 2) {
#pragma unroll
    for (int half = 0; half < 2; half++) {
      const int sc = s + half;
      uint4* raC = half ? ra1 : ra0;
      if (sc == NS - 1) asm volatile("s_waitcnt vmcnt(0)" ::: "memory");
      else              asm volatile("s_waitcnt vmcnt(4)" ::: "memory");
      __builtin_amdgcn_sched_barrier(0);
      writeA(sc, raC);
      if (sc + 2 < NS) issueA(sc + 2, raC);
      asm volatile("s_waitcnt lgkmcnt(0)" ::: "memory");
      __builtin_amdgcn_s_barrier();
      __builtin_amdgcn_sched_barrier(0);
      const unsigned char* ab = smem + (sc & 1) * 8192;
      const unsigned char* bb = smem + 16384 + (sc & 1) * 16384;
      bf16x8 af[4];
#pragma unroll
      for (int m = 0; m < 4; m++) af[m] = *(const bf16x8*)(ab + aRowB + m * 1024 + colb);
      __builtin_amdgcn_s_setprio(1);
#pragma unroll
      for (int n = 0; n < 4; n++) {
        bf16x8 bf = *(const bf16x8*)(bb + bRowB + n * 1024 + colb);
#pragma unroll
        for (int m = 0; m < 4; m++)
          acc[m][n] = __builtin_amdgcn_mfma_f32_16x16x32_bf16(af[m], bf, acc[m][n], 0, 0, 0);
      }
      __builtin_amdgcn_s_setprio(0);
      __builtin_amdgcn_sched_barrier(0);
      __builtin_amdgcn_s_barrier();
      __builtin_amdgcn_sched_barrier(0);
      if (sc + 2 < NS) issueB(sc + 2);
    }
  }
  const int rb = bm * 128 + wm * 64 + ((lane >> 4) << 2);
  const int cb = bn * 256 + wn * 64 + frow;
  float bv[4];
#pragma unroll
  for (int n = 0; n < 4; n++) bv[n] = bias[cb + n * 16];
#pragma unroll
  for (int n = 0; n < 4; n++) {
    const int col = cb + n * 16;
#pragma unroll
    for (int m = 0; m < 4; m++)
#pragma unroll
      for (int i = 0; i < 4; i++)
        C[(size_t)(rb + m * 16 + i) * ldcE + ccol0 + col] = f2b(acc[m][n][i] + bv[n]);
  }
  const int slot = bn * 4 + wn;
#pragma unroll
  for (int m = 0; m < 4; m++)
#pragma unroll
    for (int i = 0; i < 4; i++) {
      float s = 0.f, s2 = 0.f;
#pragma unroll
      for (int n = 0; n < 4; n++) {
        float v = acc[m][n][i] + bv[n];
        s += v; s2 = fmaf(v, v, s2);
      }
#pragma unroll
      for (int off = 1; off <= 8; off <<= 1) { s += __shfl_xor(s, off); s2 += __shfl_xor(s2, off); }
      if (frow == 0) statsOut[(size_t)(rb + m * 16 + i) * 16 + slot] = make_float2(s, s2);
    }
}

// ---- 128x256 ring-2 GEMM, FUSED LayerNorm+ReLU A-staging (fus) + stats2 out ----
__global__ __launch_bounds__(512, 4)
void gemm_fusLN(const unsigned short* __restrict__ A,   // fused bf16 [M][1024]
                const unsigned short* __restrict__ Bt,  // wT_fus [512][1024]
                const float2* __restrict__ statsIn,     // [M][16] partial (s,s2)
                const float* __restrict__ lng, const float* __restrict__ lnb,
                const float* __restrict__ bias,
                unsigned short* __restrict__ C,         // fused2 [M][512]
                int NBN, float2* __restrict__ statsOut) {
  constexpr int NS = 32;
  __shared__ __align__(16) unsigned char smem[57344];
  const int tid = threadIdx.x;
  const int lane = tid & 63, w = tid >> 6;
  const int swz = pair_swz(blockIdx.x, gridDim.x);
  const int bm = swz / NBN, bn = swz - bm * NBN;

  const int sslot = (tid & 3) ^ ((tid >> 3) & 3);
  const int srow = tid >> 2;
  const unsigned short* aG = A + (size_t)(bm * 128 + srow) * 1024 + sslot * 8;
  const unsigned char* bG = (const unsigned char*)Bt + (size_t)(bn * 256 + srow) * 2048 + sslot * 16;
  unsigned char* laBase = smem + srow * 64 + (tid & 3) * 16;
  unsigned char* lbBase = smem + 16384 + w * 1024;

  {
    const float* src = (w < 4) ? (lng + w * 256 + lane * 4)
                               : (lnb + (w - 4) * 256 + lane * 4);
    unsigned char* dst = smem + 49152 + w * 1024;
    async_copy16(src, dst);
  }
  asm volatile("s_waitcnt vmcnt(0)" ::: "memory");
  __builtin_amdgcn_s_barrier();

  float ssum = 0.f, ssq = 0.f;
  {
    const float2* sp = statsIn + (size_t)(bm * 128 + srow) * 16;
#pragma unroll
    for (int j = 0; j < 16; j++) { float2 p = sp[j]; ssum += p.x; ssq += p.y; }
  }
  const float mu = ssum * (1.f / 1024.f);
  const float rs = rsqrtf(ssq * (1.f / 1024.f) - mu * mu + 1e-5f);
  const float* gl = (const float*)(smem + 49152);
  const float* bl = (const float*)(smem + 53248);

  uint4 ra0, ra1;

  auto issueA = [&](int s, uint4* ra) {
    *ra = *(const uint4*)(aG + (size_t)s * 32);
  };
  auto issueB = [&](int s) {
    const int slot = s & 1;
    const unsigned char* sb = bG + (size_t)s * 64;
    async_copy16(sb, lbBase + slot * 16384);
    async_copy16(sb + 128 * 2048, lbBase + slot * 16384 + 8192);
  };
  auto writeA = [&](int s, const uint4* ra) {
    const int slot = s & 1;
    const int k0 = s * 32 + sslot * 8;
    float x[8]; unpack8(*ra, x);
    float4 g0 = *(const float4*)(gl + k0), g1 = *(const float4*)(gl + k0 + 4);
    float4 t0 = *(const float4*)(bl + k0), t1 = *(const float4*)(bl + k0 + 4);
    float y0 = fmaxf(fmaf((x[0] - mu) * rs, g0.x, t0.x), 0.f);
    float y1 = fmaxf(fmaf((x[1] - mu) * rs, g0.y, t0.y), 0.f);
    float y2 = fmaxf(fmaf((x[2] - mu) * rs, g0.z, t0.z), 0.f);
    float y3 = fmaxf(fmaf((x[3] - mu) * rs, g0.w, t0.w), 0.f);
    float y4 = fmaxf(fmaf((x[4] - mu) * rs, g1.x, t1.x), 0.f);
    float y5 = fmaxf(fmaf((x[5] - mu) * rs, g1.y, t1.y), 0.f);
    float y6 = fmaxf(fmaf((x[6] - mu) * rs, g1.z, t1.z), 0.f);
    float y7 = fmaxf(fmaf((x[7] - mu) * rs, g1.w, t1.w), 0.f);
    uint4 u;
    u.x = pack2(y0, y1); u.y = pack2(y2, y3);
    u.z = pack2(y4, y5); u.w = pack2(y6, y7);
    *(uint4*)(laBase + slot * 8192) = u;
  };

  const int wm = w >> 2, wn = w & 3;
  const int frow = lane & 15;
  const int colb = (((lane >> 4) ^ ((frow >> 1) & 3)) << 4);
  const int aRowB = (wm * 64 + frow) * 64;
  const int bRowB = (wn * 64 + frow) * 64;

  f32x4 acc[4][4];
#pragma unroll
  for (int m = 0; m < 4; m++)
#pragma unroll
    for (int n = 0; n < 4; n++) acc[m][n] = (f32x4){0.f, 0.f, 0.f, 0.f};

  issueA(0, &ra0); issueB(0);
  issueA(1, &ra1); issueB(1);

#pragma unroll 1
  for (int s = 0; s < NS; s += 2) {
#pragma unroll
    for (int half = 0; half < 2; half++) {
      const int sc = s + half;
      uint4* raC = half ? &ra1 : &ra0;
      if (sc == NS - 1) asm volatile("s_waitcnt vmcnt(0)" ::: "memory");
      else              asm volatile("s_waitcnt vmcnt(3)" ::: "memory");
      __builtin_amdgcn_sched_barrier(0);
      writeA(sc, raC);
      if (sc + 2 < NS) issueA(sc + 2, raC);
      asm volatile("s_waitcnt lgkmcnt(0)" ::: "memory");
      __builtin_amdgcn_s_barrier();
      __builtin_amdgcn_sched_barrier(0);
      const unsigned char* ab = smem + (sc & 1) * 8192;
      const unsigned char* bb = smem + 16384 + (sc & 1) * 16384;
      bf16x8 af[4];
#pragma unroll
      for (int m = 0; m < 4; m++) af[m] = *(const bf16x8*)(ab + aRowB + m * 1024 + colb);
      __builtin_amdgcn_s_setprio(1);
#pragma unroll
      for (int n = 0; n < 4; n++) {
        bf16x8 bf = *(const bf16x8*)(bb + bRowB + n * 1024 + colb);
#pragma unroll
        for (int m = 0; m < 4; m++)
          acc[m][n] = __builtin_amdgcn_mfma_f32_16x16x32_bf16(af[m], bf, acc[m][n], 0, 0, 0);
      }
      __builtin_amdgcn_s_setprio(0);
      __builtin_amdgcn_sched_barrier(0);
      __builtin_amdgcn_s_barrier();
      __builtin_amdgcn_sched_barrier(0);
      if (sc + 2 < NS) issueB(sc + 2);
    }
  }
  const int rb = bm * 128 + wm * 64 + ((lane >> 4) << 2);
  const int cb = bn * 256 + wn * 64 + frow;
  float bv[4];
#pragma unroll
  for (int n = 0; n < 4; n++) bv[n] = bias[cb + n * 16];
#pragma unroll
  for (int n = 0; n < 4; n++) {
    const int col = cb + n * 16;
#pragma unroll
    for (int m = 0; m < 4; m++)
#pragma unroll
      for (int i = 0; i < 4; i++)
        C[(size_t)(rb + m * 16 + i) * 512 + col] = f2b(acc[m][n][i] + bv[n]);
  }
  const int slot = bn * 4 + wn;
#pragma unroll
  for (int m = 0; m < 4; m++)
#pragma unroll
    for (int i = 0; i < 4; i++) {
      float s = 0.f, s2 = 0.f;
#pragma unroll
      for (int n = 0; n < 4; n++) {
        float v = acc[m][n][i] + bv[n];
        s += v; s2 = fmaf(v, v, s2);
      }
#pragma unroll
      for (int off = 1; off <= 8; off <<= 1) { s += __shfl_xor(s, off); s2 += __shfl_xor(s2, off); }
      if (frow == 0) statsOut[(size_t)(rb + m * 16 + i) * 8 + slot] = make_float2(s, s2);
    }
}

// ---- 128x128 ring-2 cls GEMM with FUSED LN+ReLU A-staging + score scatter ----
__global__ __launch_bounds__(512, 4)
void gemm_clsLN(const unsigned short* __restrict__ A,   // fused2 bf16 [M][512]
                const unsigned short* __restrict__ Bt,  // wT_cls [128][512]
                const float2* __restrict__ statsIn,     // [M][8] partial (s,s2)
                const float* __restrict__ lng, const float* __restrict__ lnb,
                const float* __restrict__ bias,
                float* __restrict__ C,                  // logits [M][50]
                const int* __restrict__ pidx,
                unsigned long long* __restrict__ scat) {
  constexpr int NS = 16;
  __shared__ __align__(16) unsigned char smem[36864];
  const int tid = threadIdx.x;
  const int lane = tid & 63, w = tid >> 6;
  const int cpx = gridDim.x >> 3;
  const int bm = (blockIdx.x & 7) * cpx + (blockIdx.x >> 3);

  const int sslot = (tid & 3) ^ ((tid >> 3) & 3);
  const int srow = tid >> 2;
  const unsigned short* aG = A + (size_t)(bm * 128 + srow) * 512 + sslot * 8;
  const unsigned char* bG = (const unsigned char*)Bt + (size_t)srow * 1024 + sslot * 16;
  unsigned char* laBase = smem + srow * 64 + (tid & 3) * 16;
  unsigned char* lbBase = smem + 16384 + w * 1024;

  if (w < 4) {
    const float* src = (w < 2) ? (lng + w * 256 + lane * 4)
                               : (lnb + (w - 2) * 256 + lane * 4);
    unsigned char* dst = smem + 32768 + ((w < 2) ? w * 1024 : 2048 + (w - 2) * 1024);
    async_copy16(src, dst);
  }
  asm volatile("s_waitcnt vmcnt(0)" ::: "memory");
  __builtin_amdgcn_s_barrier();

  float ssum = 0.f, ssq = 0.f;
  {
    const float2* sp = statsIn + (size_t)(bm * 128 + srow) * 8;
#pragma unroll
    for (int j = 0; j < 8; j++) { float2 p = sp[j]; ssum += p.x; ssq += p.y; }
  }
  const float mu = ssum * (1.f / 512.f);
  const float rs = rsqrtf(ssq * (1.f / 512.f) - mu * mu + 1e-5f);
  const float* gl = (const float*)(smem + 32768);
  const float* bl = (const float*)(smem + 34816);

  uint4 ra0, ra1;
  auto issueA = [&](int s, uint4* ra) { *ra = *(const uint4*)(aG + (size_t)s * 32); };
  auto issueB = [&](int s) {
    async_copy16(bG + (size_t)s * 64, lbBase + (s & 1) * 8192);
  };
  auto writeA = [&](int s, const uint4* ra) {
    const int slot = s & 1;
    const int k0 = s * 32 + sslot * 8;
    float x[8]; unpack8(*ra, x);
    float4 g0 = *(const float4*)(gl + k0), g1 = *(const float4*)(gl + k0 + 4);
    float4 t0 = *(const float4*)(bl + k0), t1 = *(const float4*)(bl + k0 + 4);
    float y0 = fmaxf(fmaf((x[0] - mu) * rs, g0.x, t0.x), 0.f);
    float y1 = fmaxf(fmaf((x[1] - mu) * rs, g0.y, t0.y), 0.f);
    float y2 = fmaxf(fmaf((x[2] - mu) * rs, g0.z, t0.z), 0.f);
    float y3 = fmaxf(fmaf((x[3] - mu) * rs, g0.w, t0.w), 0.f);
    float y4 = fmaxf(fmaf((x[4] - mu) * rs, g1.x, t1.x), 0.f);
    float y5 = fmaxf(fmaf((x[5] - mu) * rs, g1.y, t1.y), 0.f);
    float y6 = fmaxf(fmaf((x[6] - mu) * rs, g1.z, t1.z), 0.f);
    float y7 = fmaxf(fmaf((x[7] - mu) * rs, g1.w, t1.w), 0.f);
    uint4 u;
    u.x = pack2(y0, y1); u.y = pack2(y2, y3);
    u.z = pack2(y4, y5); u.w = pack2(y6, y7);
    *(uint4*)(laBase + slot * 8192) = u;
  };

  const int wm = w >> 1, wn = w & 1;
  const int frow = lane & 15;
  const int colb = (((lane >> 4) ^ ((frow >> 1) & 3)) << 4);
  const int aRowB = (wm * 32 + frow) * 64;
  const int bRowB = (wn * 64 + frow) * 64;

  f32x4 acc[2][4];
#pragma unroll
  for (int m = 0; m < 2; m++)
#pragma unroll
    for (int n = 0; n < 4; n++) acc[m][n] = (f32x4){0.f, 0.f, 0.f, 0.f};

  issueA(0, &ra0); issueB(0);
  issueA(1, &ra1); issueB(1);

#pragma unroll 1
  for (int s = 0; s < NS; s += 2) {
#pragma unroll
    for (int half = 0; half < 2; half++) {
      const int sc = s + half;
      uint4* raC = half ? &ra1 : &ra0;
      if (sc == NS - 1) asm volatile("s_waitcnt vmcnt(0)" ::: "memory");
      else              asm volatile("s_waitcnt vmcnt(2)" ::: "memory");
      __builtin_amdgcn_sched_barrier(0);
      writeA(sc, raC);
      if (sc + 2 < NS) issueA(sc + 2, raC);
      asm volatile("s_waitcnt lgkmcnt(0)" ::: "memory");
      __builtin_amdgcn_s_barrier();
      __builtin_amdgcn_sched_barrier(0);
      const unsigned char* ab = smem + (sc & 1) * 8192;
      const unsigned char* bb = smem + 16384 + (sc & 1) * 8192;
      bf16x8 af[2];
#pragma unroll
      for (int m = 0; m < 2; m++) af[m] = *(const bf16x8*)(ab + aRowB + m * 1024 + colb);
      __builtin_amdgcn_s_setprio(1);
#pragma unroll
      for (int n = 0; n < 4; n++) {
        bf16x8 bf = *(const bf16x8*)(bb + bRowB + n * 1024 + colb);
#pragma unroll
        for (int m = 0; m < 2; m++)
          acc[m][n] = __builtin_amdgcn_mfma_f32_16x16x32_bf16(af[m], bf, acc[m][n], 0, 0, 0);
      }
      __builtin_amdgcn_s_setprio(0);
      __builtin_amdgcn_sched_barrier(0);
      __builtin_amdgcn_s_barrier();
      __builtin_amdgcn_sched_barrier(0);
      if (sc + 2 < NS) issueB(sc + 2);
    }
  }
  const int rb = bm * 128 + wm * 32 + ((lane >> 4) << 2);
  const int cbl = wn * 64 + frow;
#pragma unroll
  for (int n = 0; n < 4; n++) {
    const int col = cbl + n * 16;
    const float bv = (col < OUTC) ? bias[col] : 0.f;
#pragma unroll
    for (int m = 0; m < 2; m++)
#pragma unroll
      for (int i = 0; i < 4; i++) {
        const int row = rb + m * 16 + i;
        if (col < OUTC) C[(size_t)row * OUTC + col] = acc[m][n][i] + bv;
      }
  }
  if (wn == 0) {
#pragma unroll
    for (int m = 0; m < 2; m++)
#pragma unroll
      for (int i = 0; i < 4; i++) {
        float mx = -1e30f;
#pragma unroll
        for (int n = 0; n < 4; n++) {
          const int col = n * 16 + frow;
          float v = acc[m][n][i] + ((col < OUTC) ? bias[col] : 0.f);
          if (col < OUTC) mx = fmaxf(mx, v);
        }
        mx = fmaxf(mx, __shfl_xor(mx, 1));
        mx = fmaxf(mx, __shfl_xor(mx, 2));
        mx = fmaxf(mx, __shfl_xor(mx, 4));
        mx = fmaxf(mx, __shfl_xor(mx, 8));
        if (frow == 0) {
          const int row = rb + m * 16 + i;
          float sc = 1.f / (1.f + expf(-mx));
          int b = row >> 12, p = row & 4095;
          int s = pidx[2 * row], o = pidx[2 * row + 1];
          unsigned long long key = (((unsigned long long)(p + 1)) << 32) |
                                   (unsigned long long)__float_as_uint(sc);
          atomicMax(&scat[((size_t)(b * N_ + s) << 7) + o], key);
        }
      }
  }
}

__global__ void relmat_kernel(const unsigned long long* __restrict__ scat, float* __restrict__ out) {
  int i = blockIdx.x * blockDim.x + threadIdx.x;
  if (i >= B_ * N_ * N_) return;
  unsigned long long v = scat[i];
  out[i] = v ? __uint_as_float((unsigned)(v & 0xffffffffu)) : 0.f;
}

extern "C" void kernel_launch(void* const* d_in, const int* in_sizes, int n_in,
                              void* d_out, int out_size, void* d_ws, size_t ws_size,
                              hipStream_t stream) {
  const float* visual_feat = (const float*)d_in[0];
  const float* box_info    = (const float*)d_in[1];
  const float* pred_logits = (const float*)d_in[2];
  const int*   pair_idx    = (const int*)d_in[3];
  const float* obj_sem_w   = (const float*)d_in[4];
  const float* pos_w1 = (const float*)d_in[5];
  const float* pos_b1 = (const float*)d_in[6];
  const float* pos_w2 = (const float*)d_in[7];
  const float* pos_b2 = (const float*)d_in[8];
  const float* vis_w  = (const float*)d_in[9];
  const float* vis_b  = (const float*)d_in[10];
  const float* geo_w  = (const float*)d_in[11];
  const float* geo_b  = (const float*)d_in[12];
  const float* fus_g  = (const float*)d_in[13];
  const float* fus_bt = (const float*)d_in[14];
  const float* fus_w  = (const float*)d_in[15];
  const float* fus_b  = (const float*)d_in[16];
  const float* cls_g  = (const float*)d_in[17];
  const float* cls_bt = (const float*)d_in[18];
  const float* cls_w  = (const float*)d_in[19];
  const float* cls_b  = (const float*)d_in[20];

  char* ws = (char*)d_ws;
  size_t off = 0;
  auto alloc = [&](size_t bytes) { char* p = ws + off; off += (bytes + 255) & ~(size_t)255; return p; };
  unsigned short* fused = (unsigned short*)alloc((size_t)M_ * 1024 * 2);      // 134 MB
  unsigned short* fused2 = (unsigned short*)alloc((size_t)M_ * 512 * 2);      // 67 MB
  unsigned short* nodeFb = (unsigned short*)alloc((size_t)B_ * N_ * NODEF * 2);
  unsigned short* wT_vis = (unsigned short*)alloc((size_t)512 * 1024 * 2);
  unsigned short* wT_geo = (unsigned short*)alloc((size_t)512 * KGEOP * 2);
  unsigned short* wT_fus = (unsigned short*)alloc((size_t)512 * 1024 * 2);
  unsigned short* wT_cls = (unsigned short*)alloc((size_t)128 * 512 * 2);
  unsigned long long* scat = (unsigned long long*)alloc((size_t)B_ * N_ * N_ * 8);
  float2* statsP1 = (float2*)alloc((size_t)M_ * 16 * 8);                      // 8 MB
  float2* statsP2 = (float2*)alloc((size_t)M_ * 8 * 8);                       // 4 MB

  float* out_logits = (float*)d_out;
  float* out_rel = out_logits + (size_t)M_ * OUTC;

  prep_kernel<<<dim3((PREP_TOT + 255) / 256), 256, 0, stream>>>(
      (uint4*)scat, vis_w, wT_vis, geo_w, wT_geo, fus_w, wT_fus, cls_w, wT_cls);
  node_kernel<<<dim3(B_ * N_), 128, 0, stream>>>(box_info, pred_logits, obj_sem_w,
                                                 pos_w1, pos_b1, pos_w2, pos_b2, nodeFb);
  // geo: gather GEMM -> fused[:,512:] + partial row stats (slots 8..15)
  gemm_geo<<<dim3(1024), 512, 0, stream>>>(wT_geo, KGEOP, geo_b,
                                           fused, 1024, 512, KGEOP / 32, 2,
                                           pair_idx, nodeFb, (const unsigned short*)scat,
                                           statsP1);
  // vis: f32+relu GEMM -> fused[:,0:512] + partial row stats (slots 0..7)
  gemm256f3<<<dim3(1024), 512, 0, stream>>>(visual_feat, wT_vis, vis_b,
                                            fused, 1024, 0, 2, statsP1);
  // fus: LN(stats combine)+relu in A-staging -> fused2 + partial stats2 (8 slots)
  gemm_fusLN<<<dim3(1024), 512, 0, stream>>>(fused, wT_fus, statsP1, fus_g, fus_bt,
                                             fus_b, fused2, 2, statsP2);
  // cls: LN(stats2)+relu in A-staging -> logits + fused score scatter
  gemm_clsLN<<<dim3(512), 512, 0, stream>>>(fused2, wT_cls, statsP2, cls_g, cls_bt,
                                            cls_b, out_logits, pair_idx, scat);
  relmat_kernel<<<dim3((B_ * N_ * N_) / 256), 256, 0, stream>>>(scat, out_rel);
}